// Round 17
// baseline (245.850 us; speedup 1.0000x reference)
//
#include <hip/hip_runtime.h>
#include <stdint.h>

#define NL 2048
#define ND 256
#define KVB 32
#define QB 128                      // paired q-tiles: 8 waves, 128 rows/block
#define NPAIR 16                    // 128-row pairs per batch
#define NT_ALL (NL / KVB)           // 64 kv tiles per batch
#define CHUNK 12                    // kv tiles per block -> 56 chunks/batch, grid 448
#define NCHUNKS_B 56                // 6 (pair0 spans all 64) + sum_{j=1..15} ceil((4j+4)/12)
#define TILE_BYTES (KVB * ND * 2)   // 16 KB image per kv tile
#define IMG (8 * NT_ALL * TILE_BYTES)
#define WS_MB 256                   // 512 u32 packed mask bits (2 KB)
#define WS_K (WS_MB + 2048)
#define WS_V (WS_K + IMG)
#define WS_P (WS_V + IMG)
#define PART_BYTES (QB * ND * 2 + QB * 8)  // bf16 acc + fp32 m,l = 66560

typedef __attribute__((ext_vector_type(8))) short short8;
typedef __attribute__((ext_vector_type(4))) short short4v;
typedef __attribute__((ext_vector_type(4))) float f32x4;
typedef __attribute__((ext_vector_type(4))) unsigned int u32x4;
typedef __attribute__((ext_vector_type(8))) unsigned short ushort8;

__device__ __forceinline__ unsigned short bf16rne(float x) {
  unsigned u = __builtin_bit_cast(unsigned, x);
  u += 0x7FFFu + ((u >> 16) & 1u);
  return (unsigned short)(u >> 16);
}

__device__ __forceinline__ short8 cvt8(float4 a, float4 b, float scale) {
  short8 v;
  v[0] = (short)bf16rne(a.x * scale);
  v[1] = (short)bf16rne(a.y * scale);
  v[2] = (short)bf16rne(a.z * scale);
  v[3] = (short)bf16rne(a.w * scale);
  v[4] = (short)bf16rne(b.x * scale);
  v[5] = (short)bf16rne(b.y * scale);
  v[6] = (short)bf16rne(b.z * scale);
  v[7] = (short)bf16rne(b.w * scale);
  return v;
}

// Detect mask storage (int32 words vs byte bools) and pack one 32-bit mask
// word per kv-tile: bit k = mask[b, tix*32+k]. 1 block x 512 threads.
__global__ __launch_bounds__(512)
void mask_pack(const unsigned* __restrict__ M, unsigned* __restrict__ MB) {
  __shared__ int badS;
  if (threadIdx.x == 0) badS = 0;
  __syncthreads();
  bool bad = false;
  for (int i = threadIdx.x; i < 4096; i += 512)
    if (M[i] > 1u) bad = true;
  if (__any(bad) && (threadIdx.x & 63) == 0) badS = 1;
  __syncthreads();
  const int byteMode = badS;
  const int i = threadIdx.x;  // kv-tile id = b*64 + tix
  unsigned m = 0;
  for (int j = 0; j < 32; ++j) {
    int mv = byteMode ? (int)((const unsigned char*)M)[i * 32 + j] : (int)M[i * 32 + j];
    m |= (mv ? 1u : 0u) << j;
  }
  MB[i] = m;
}

// One-shot K,V fp32->bf16 conversion. K stored as XOR-swizzled LDS tile
// images, V in the tr-read subtile layout.
__global__ __launch_bounds__(128)
void convert_kv(const float* __restrict__ K, const float* __restrict__ V,
                unsigned char* __restrict__ ws) {
  const int t = blockIdx.x;  // b*64 + tix  (32-row tiles)
  const int b = t >> 6, tix = t & 63;
  const float* kt = K + ((size_t)b * NL + tix * KVB) * ND;
  const float* vt = V + ((size_t)b * NL + tix * KVB) * ND;
  unsigned char* kd = ws + WS_K + (size_t)t * TILE_BYTES;
  unsigned char* vd = ws + WS_V + (size_t)t * TILE_BYTES;
#pragma unroll
  for (int it = 0; it < 8; ++it) {
    int idx = it * 128 + threadIdx.x;
    int row = idx >> 5, u = idx & 31, f = u * 8;
    const float4* kp = (const float4*)(kt + (size_t)row * ND + f);
    int kb = (row * 512 + f * 2) ^ ((row & 7) << 4);
    *(short8*)(kd + kb) = cvt8(kp[0], kp[1], 1.0f);
    const float4* vp = (const float4*)(vt + (size_t)row * ND + f);
    int vb = (row >> 2) * 2048 + (u >> 1) * 128 + (row & 3) * 32 + (u & 1) * 16;
    *(short8*)(vd + vb) = cvt8(vp[0], vp[1], 1.0f);
  }
}

// Flash attention fwd: 128 q-rows/block (8 waves), ONE K/V stream feeds both
// 64-row halves -> staged tiles drop 46%, TLP doubles to 4 waves/SIMD.
// Swapped-QK in-register softmax per wave (r15), counted-vmcnt pipeline
// (K 3-buf, V 2-buf, raw barriers; V issued before K so K keeps 2-iter lead).
// Pair 0 spans all 64 kv tiles (-10000-tier tie semantics via LSE combine);
// fully-masked tiles for lower-half rows are exact (underflow to 0).
__global__ __launch_bounds__(512, 4)
void attn_fwd(const float* __restrict__ Qg, const unsigned* __restrict__ MBg,
              unsigned char* ws) {
  __shared__ unsigned short Ks[3][KVB * ND];   // 48 KB (also epilogue scratch)
  __shared__ unsigned short Vs[2][KVB * ND];   // 32 KB  => 80 KB total

  const int tid = threadIdx.x;
  const int wv = tid >> 6;      // wave 0..7
  const int lane = tid & 63;
  const int g = lane >> 4;      // 4-lane-group id
  const int cc = lane & 15;     // lane-in-group

  // ---- decode fid -> (b, pair j, chunk c)
  const int fid = blockIdx.x;
  const int b = fid / NCHUNKS_B;
  int rem = fid - b * NCHUNKS_B;
  int j = 0, c = 0, pbase = 0;
  if (rem < 6) {
    j = 0; c = rem; pbase = 0;
  } else {
    rem -= 6; pbase = 6;
    for (j = 1; j < NPAIR; ++j) {
      int ncq = (4 * j + 4 + CHUNK - 1) / CHUNK;
      if (rem < ncq) { c = rem; break; }
      rem -= ncq; pbase += ncq;
    }
  }
  const int qb = j * QB;
  const int nt_s = (j == 0) ? NT_ALL : (4 * j + 4);
  const int t0 = c * CHUNK;
  const int t1 = min(nt_s, t0 + CHUNK);
  unsigned char* pp = ws + WS_P + (size_t)(b * NCHUNKS_B + pbase + c) * PART_BYTES;
  unsigned short* ppA = (unsigned short*)pp;
  float* ppM = (float*)(pp + QB * ND * 2);
  float* ppL = ppM + QB;

  auto stage_K = [&](int tix, int bi) {
    const unsigned char* kg = ws + WS_K + ((size_t)(b * NT_ALL + tix)) * TILE_BYTES;
#pragma unroll
    for (int s = 0; s < 2; ++s) {
      const int seg = wv * 2 + s;  // 16 segs x 1KB; wave-uniform LDS dest
      __builtin_amdgcn_global_load_lds(
          (const __attribute__((address_space(1))) unsigned int*)(kg + seg * 1024 + lane * 16),
          (__attribute__((address_space(3))) unsigned int*)((unsigned char*)&Ks[bi][0] + seg * 1024),
          16, 0, 0);
    }
  };
  auto stage_V = [&](int tix, int bi) {
    const unsigned char* vg = ws + WS_V + ((size_t)(b * NT_ALL + tix)) * TILE_BYTES;
#pragma unroll
    for (int s = 0; s < 2; ++s) {
      const int seg = wv * 2 + s;
      __builtin_amdgcn_global_load_lds(
          (const __attribute__((address_space(1))) unsigned int*)(vg + seg * 1024 + lane * 16),
          (__attribute__((address_space(3))) unsigned int*)((unsigned char*)&Vs[bi][0] + seg * 1024),
          16, 0, 0);
    }
  };

  // ---- Q fragments direct from fp32 (once per block), scaled 1/16
  const float* qp = Qg + ((size_t)b * NL + (qb + 16 * wv + cc)) * ND;
  short8 qf[8];
#pragma unroll
  for (int ch = 0; ch < 8; ++ch) {
    int f = ch * 32 + g * 8;
    float4 a0 = *reinterpret_cast<const float4*>(qp + f);
    float4 a1 = *reinterpret_cast<const float4*>(qp + f + 4);
    qf[ch] = cvt8(a0, a1, 0.0625f);
  }
  const int qg = qb + 16 * wv + cc;  // this lane's q-row (swapped layout)

  f32x4 acc[16];
#pragma unroll
  for (int i = 0; i < 16; ++i) acc[i] = (f32x4){0.f, 0.f, 0.f, 0.f};
  float m_run = -3.0e38f, l_run = 0.f;   // per-lane scalars (row = cc)

  // ---- prologue: retire Q loads (FIFO must contain only DMA), then prime:
  // K(t0), V(t0), K(t0+1)  [V-before-later-K keeps steady counts valid]
  asm volatile("s_waitcnt vmcnt(0)" ::: "memory");
  __builtin_amdgcn_sched_barrier(0);
  stage_K(t0, t0 % 3);
  stage_V(t0, t0 & 1);
  if (t0 + 1 < t1) stage_K(t0 + 1, (t0 + 1) % 3);

  for (int tix = t0; tix < t1; ++tix) {
    // issue V(t+1) then K(t+2): FIFO order preserves K's 2-iter lead
    if (tix + 1 < t1) stage_V(tix + 1, (tix + 1) & 1);
    if (tix + 2 < t1) stage_K(tix + 2, (tix + 2) % 3);
    // counted wait: retire own K(t),V(t); newer prefetch stays in flight
    if (tix + 2 < t1) {
      asm volatile("s_waitcnt vmcnt(6)" ::: "memory");
    } else if (tix + 1 < t1) {
      asm volatile("s_waitcnt vmcnt(4)" ::: "memory");
    } else {
      asm volatile("s_waitcnt vmcnt(0)" ::: "memory");
    }
    __builtin_amdgcn_sched_barrier(0);
    __builtin_amdgcn_s_barrier();   // all waves' tile-t staging visible
    __builtin_amdgcn_sched_barrier(0);

    const int kv0 = tix * KVB;
    const unsigned mb = MBg[b * NT_ALL + tix];  // wave-uniform -> s_load

    // ---- S^T = K Q^T: lane (g,cc) gets S[q=cc][kv0+4g+r] (s0), +16 (s1)
    const char* ksB = (const char*)&Ks[tix % 3][0];
    f32x4 s0 = {0.f, 0.f, 0.f, 0.f}, s1 = {0.f, 0.f, 0.f, 0.f};
    __builtin_amdgcn_s_setprio(1);
#pragma unroll
    for (int ch = 0; ch < 8; ++ch) {
      int cbase = ch * 64 + g * 16;
      int b0 = (cc * 512 + cbase) ^ ((cc & 7) << 4);
      int b1 = ((cc + 16) * 512 + cbase) ^ ((cc & 7) << 4);
      short8 k0 = *reinterpret_cast<const short8*>(ksB + b0);
      short8 k1 = *reinterpret_cast<const short8*>(ksB + b1);
      s0 = __builtin_amdgcn_mfma_f32_16x16x32_bf16(k0, qf[ch], s0, 0, 0, 0);
      s1 = __builtin_amdgcn_mfma_f32_16x16x32_bf16(k1, qf[ch], s1, 0, 0, 0);
    }
    __builtin_amdgcn_s_setprio(0);

    // ---- biases: padding from packed bits + causal, per element
#pragma unroll
    for (int r = 0; r < 4; ++r) {
      int k0i = 4 * g + r, k1i = 16 + 4 * g + r;
      if (!((mb >> k0i) & 1u)) s0[r] -= 10000.f;
      if (!((mb >> k1i) & 1u)) s1[r] -= 10000.f;
      if (kv0 + k0i > qg) s0[r] -= 10000.f;
      if (kv0 + k1i > qg) s1[r] -= 10000.f;
    }

    // ---- online softmax, row-local: in-lane tree + 2 cross-lane rounds
    float rmax = fmaxf(fmaxf(fmaxf(s0[0], s0[1]), fmaxf(s0[2], s0[3])),
                       fmaxf(fmaxf(s1[0], s1[1]), fmaxf(s1[2], s1[3])));
    rmax = fmaxf(rmax, __shfl_xor(rmax, 16));
    rmax = fmaxf(rmax, __shfl_xor(rmax, 32));
    bool grow = (rmax > m_run + 8.f);
    if (__any(grow)) {  // wave-uniform; exact in the LSE combine
      float mn = fmaxf(m_run, rmax);
      float alpha = __expf(m_run - mn);
      m_run = mn;
      l_run *= alpha;   // per-lane partial l; alpha row-uniform -> exact
      f32x4 av;
#pragma unroll
      for (int r = 0; r < 4; ++r) av[r] = __shfl(alpha, 20 * g + r);
#pragma unroll
      for (int i = 0; i < 16; ++i) acc[i] *= av;
    }
    float p0[4], p1[4];
#pragma unroll
    for (int r = 0; r < 4; ++r) {
      p0[r] = __expf(s0[r] - m_run);
      p1[r] = __expf(s1[r] - m_run);
    }
    l_run += (p0[0] + p0[1]) + (p0[2] + p0[3]) +
             (p1[0] + p1[1]) + (p1[2] + p1[3]);

    // ---- build PV A-fragment in-register: pa[j] = P[cc][kv0+8g+j] (bf16)
    unsigned a0, a1, b0w, b1w;
    asm("v_cvt_pk_bf16_f32 %0, %1, %2" : "=v"(a0) : "v"(p0[0]), "v"(p0[1]));
    asm("v_cvt_pk_bf16_f32 %0, %1, %2" : "=v"(a1) : "v"(p0[2]), "v"(p0[3]));
    asm("v_cvt_pk_bf16_f32 %0, %1, %2" : "=v"(b0w) : "v"(p1[0]), "v"(p1[1]));
    asm("v_cvt_pk_bf16_f32 %0, %1, %2" : "=v"(b1w) : "v"(p1[2]), "v"(p1[3]));
    const int srcLo = cc + ((g & 1) << 5);  // lane of source group 2*(g&1)
    const int srcHi = srcLo + 16;           // lane of source group 2*(g&1)+1
    unsigned wa0 = (unsigned)__shfl((int)a0, srcLo);
    unsigned wa1 = (unsigned)__shfl((int)a1, srcLo);
    unsigned wa2 = (unsigned)__shfl((int)a0, srcHi);
    unsigned wa3 = (unsigned)__shfl((int)a1, srcHi);
    unsigned wb0 = (unsigned)__shfl((int)b0w, srcLo);
    unsigned wb1 = (unsigned)__shfl((int)b1w, srcLo);
    unsigned wb2 = (unsigned)__shfl((int)b0w, srcHi);
    unsigned wb3 = (unsigned)__shfl((int)b1w, srcHi);
    const bool hiHalf = (g >= 2);
    u32x4 paw = {hiHalf ? wb0 : wa0, hiHalf ? wb1 : wa1,
                 hiHalf ? wb2 : wa2, hiHalf ? wb3 : wa3};
    short8 pa = __builtin_bit_cast(short8, paw);

    // ---- O += P V: 32 tr-reads issued; counted lgkmcnt(15) overlaps the
    // first MFMA batch with in-flight tr-reads (DS completes in order).
    const unsigned va = (unsigned)(uintptr_t)&Vs[tix & 1][0] + g * 4096 + cc * 8;
    short4v lo[16], hi[16];
#pragma unroll
    for (int ft = 0; ft < 16; ++ft) {
      asm volatile("ds_read_b64_tr_b16 %0, %1 offset:%2"
                   : "=&v"(lo[ft]) : "v"(va), "i"(ft * 128) : "memory");
      asm volatile("ds_read_b64_tr_b16 %0, %1 offset:%2"
                   : "=&v"(hi[ft]) : "v"(va), "i"(ft * 128 + 2048) : "memory");
    }
    asm volatile("s_waitcnt lgkmcnt(15)" ::: "memory");  // >=17 done: ft 0..7
    __builtin_amdgcn_sched_barrier(0);
    __builtin_amdgcn_s_setprio(1);
#pragma unroll
    for (int ft = 0; ft < 8; ++ft) {
      short8 vb = __builtin_shufflevector(lo[ft], hi[ft], 0, 1, 2, 3, 4, 5, 6, 7);
      acc[ft] = __builtin_amdgcn_mfma_f32_16x16x32_bf16(pa, vb, acc[ft], 0, 0, 0);
    }
    __builtin_amdgcn_s_setprio(0);
    asm volatile("s_waitcnt lgkmcnt(0)" ::: "memory");
    __builtin_amdgcn_sched_barrier(0);
    __builtin_amdgcn_s_setprio(1);
#pragma unroll
    for (int ft = 8; ft < 16; ++ft) {
      short8 vb = __builtin_shufflevector(lo[ft], hi[ft], 0, 1, 2, 3, 4, 5, 6, 7);
      acc[ft] = __builtin_amdgcn_mfma_f32_16x16x32_bf16(pa, vb, acc[ft], 0, 0, 0);
    }
    __builtin_amdgcn_s_setprio(0);

    // ---- all waves done reading tile-t buffers before next iteration's
    // issues overwrite them (raw barrier: no counter drain)
    __builtin_amdgcn_sched_barrier(0);
    __builtin_amdgcn_s_barrier();
    __builtin_amdgcn_sched_barrier(0);
  }

  // ---- epilogue: reduce deferred l across the row's 4 lanes
  l_run += __shfl_xor(l_run, 16);
  l_run += __shfl_xor(l_run, 32);
  if (g == 0) {  // lane owns row cc of its wave's 16-row block
    ppM[16 * wv + cc] = m_run;
    ppL[16 * wv + cc] = l_run;
  }

  // transpose acc through LDS in two 64-row half-passes (32 KB of Ks)
  unsigned short* sc = &Ks[0][0];
#pragma unroll
  for (int h = 0; h < 2; ++h) {
    __syncthreads();
    if ((wv >> 2) == h) {
#pragma unroll
      for (int ft = 0; ft < 16; ++ft) {
#pragma unroll
        for (int r = 0; r < 4; ++r) {
          sc[(16 * (wv & 3) + 4 * g + r) * 256 + ft * 16 + cc] = bf16rne(acc[ft][r]);
        }
      }
    }
    __syncthreads();
    const int row = tid >> 3, oct = tid & 7;  // 512 threads: 64 rows x 8 octs
    const ushort8* src = (const ushort8*)(sc + row * 256 + oct * 32);
    ushort8* dst = (ushort8*)(ppA + (size_t)(h * 64 + row) * ND + oct * 32);
#pragma unroll
    for (int kk = 0; kk < 4; ++kk) dst[kk] = src[kk];
  }
}

// Exact log-sum-exp merge of the variable-count partials per (b, pair, half).
__global__ __launch_bounds__(256)
void attn_combine(const unsigned char* __restrict__ ws, float* __restrict__ Og) {
  const int bid = blockIdx.x;  // b(3) | pair j(4) | half(1)
  const int b = bid >> 5;
  const int j = (bid >> 1) & 15;
  const int h = bid & 1;
  const int tid = threadIdx.x;
  const int row = tid >> 2, sub = tid & 3;
  const int grow = h * 64 + row;

  int pbase = 0, nc = 6;
  if (j > 0) {
    pbase = 6;
    for (int jj = 1; jj < j; ++jj) pbase += (4 * jj + 4 + CHUNK - 1) / CHUNK;
    nc = (4 * j + 4 + CHUNK - 1) / CHUNK;
  }
  const unsigned char* p0 = ws + WS_P + (size_t)(b * NCHUNKS_B + pbase) * PART_BYTES;

  float M = -3.0e38f;
  for (int c = 0; c < nc; ++c) {
    M = fmaxf(M, *(const float*)(p0 + (size_t)c * PART_BYTES + QB * ND * 2 + grow * 4));
  }
  float L = 0.f;
  float o[64];
#pragma unroll
  for (int q = 0; q < 64; ++q) o[q] = 0.f;
  for (int c = 0; c < nc; ++c) {
    const unsigned char* pc = p0 + (size_t)c * PART_BYTES;
    float mm = *(const float*)(pc + QB * ND * 2 + grow * 4);
    float ll = *(const float*)(pc + QB * ND * 2 + QB * 4 + grow * 4);
    float s = __expf(mm - M);
    L += ll * s;
    const unsigned short* pa =
        (const unsigned short*)pc + (size_t)grow * ND + sub * 64;
#pragma unroll
    for (int kk = 0; kk < 8; ++kk) {
      ushort8 a = *(const ushort8*)(pa + kk * 8);
#pragma unroll
      for (int q = 0; q < 8; ++q) {
        unsigned u = ((unsigned)a[q]) << 16;
        o[kk * 8 + q] += __builtin_bit_cast(float, u) * s;
      }
    }
  }
  const float invL = 1.0f / L;
  float* op = Og + ((size_t)b * NL + j * QB + grow) * ND + sub * 64;
#pragma unroll
  for (int kk = 0; kk < 16; ++kk) {
    float4 v = {o[kk * 4] * invL, o[kk * 4 + 1] * invL, o[kk * 4 + 2] * invL,
                o[kk * 4 + 3] * invL};
    *(float4*)(op + kk * 4) = v;
  }
}

extern "C" void kernel_launch(void* const* d_in, const int* in_sizes, int n_in,
                              void* d_out, int out_size, void* d_ws, size_t ws_size,
                              hipStream_t stream) {
  (void)in_sizes; (void)n_in; (void)out_size; (void)ws_size;  // ~46.6MB <= 67.6MB proven (r5)
  const float* Q = (const float*)d_in[0];
  const float* K = (const float*)d_in[1];
  const float* V = (const float*)d_in[2];
  const int* M = (const int*)d_in[3];
  unsigned char* ws = (unsigned char*)d_ws;

  mask_pack<<<dim3(1), dim3(512), 0, stream>>>((const unsigned*)M,
                                               (unsigned*)(ws + WS_MB));
  convert_kv<<<dim3(512), dim3(128), 0, stream>>>(K, V, ws);
  attn_fwd<<<dim3(8 * NCHUNKS_B), dim3(512), 0, stream>>>(
      Q, (const unsigned*)(ws + WS_MB), ws);
  attn_combine<<<dim3(256), dim3(256), 0, stream>>>(ws, (float*)d_out);
}

// Round 18
// 112.697 us; speedup vs baseline: 2.1815x; 2.1815x over previous
//
#include <hip/hip_runtime.h>
#include <stdint.h>

#define NL 2048
#define ND 256
#define KVB 32
#define QB 128                      // paired q-tiles: 8 waves, 128 rows/block
#define NPAIR 16                    // 128-row pairs per batch
#define NT_ALL (NL / KVB)           // 64 kv tiles per batch
#define CHUNK 12                    // kv tiles per block -> 56 chunks/batch, grid 448
#define NCHUNKS_B 56                // 6 (pair0 spans all 64) + sum_{j=1..15} ceil((4j+4)/12)
#define TILE_BYTES (KVB * ND * 2)   // 16 KB image per kv tile
#define IMG (8 * NT_ALL * TILE_BYTES)
#define WS_MB 256                   // 512 u32 packed mask bits (2 KB)
#define WS_K (WS_MB + 2048)
#define WS_V (WS_K + IMG)
#define WS_P (WS_V + IMG)
#define PART_BYTES (QB * ND * 2 + QB * 8)  // bf16 acc + fp32 m,l = 66560

typedef __attribute__((ext_vector_type(8))) short short8;
typedef __attribute__((ext_vector_type(4))) short short4v;
typedef __attribute__((ext_vector_type(4))) float f32x4;
typedef __attribute__((ext_vector_type(4))) unsigned int u32x4;
typedef __attribute__((ext_vector_type(8))) unsigned short ushort8;

__device__ __forceinline__ unsigned short bf16rne(float x) {
  unsigned u = __builtin_bit_cast(unsigned, x);
  u += 0x7FFFu + ((u >> 16) & 1u);
  return (unsigned short)(u >> 16);
}

__device__ __forceinline__ short8 cvt8(float4 a, float4 b, float scale) {
  short8 v;
  v[0] = (short)bf16rne(a.x * scale);
  v[1] = (short)bf16rne(a.y * scale);
  v[2] = (short)bf16rne(a.z * scale);
  v[3] = (short)bf16rne(a.w * scale);
  v[4] = (short)bf16rne(b.x * scale);
  v[5] = (short)bf16rne(b.y * scale);
  v[6] = (short)bf16rne(b.z * scale);
  v[7] = (short)bf16rne(b.w * scale);
  return v;
}

// Detect mask storage (int32 words vs byte bools) and pack one 32-bit mask
// word per kv-tile: bit k = mask[b, tix*32+k]. 1 block x 512 threads.
__global__ __launch_bounds__(512)
void mask_pack(const unsigned* __restrict__ M, unsigned* __restrict__ MB) {
  __shared__ int badS;
  if (threadIdx.x == 0) badS = 0;
  __syncthreads();
  bool bad = false;
  for (int i = threadIdx.x; i < 4096; i += 512)
    if (M[i] > 1u) bad = true;
  if (__any(bad) && (threadIdx.x & 63) == 0) badS = 1;
  __syncthreads();
  const int byteMode = badS;
  const int i = threadIdx.x;  // kv-tile id = b*64 + tix
  unsigned m = 0;
  for (int j = 0; j < 32; ++j) {
    int mv = byteMode ? (int)((const unsigned char*)M)[i * 32 + j] : (int)M[i * 32 + j];
    m |= (mv ? 1u : 0u) << j;
  }
  MB[i] = m;
}

// One-shot K,V fp32->bf16 conversion. K stored as XOR-swizzled LDS tile
// images, V in the tr-read subtile layout.
__global__ __launch_bounds__(128)
void convert_kv(const float* __restrict__ K, const float* __restrict__ V,
                unsigned char* __restrict__ ws) {
  const int t = blockIdx.x;  // b*64 + tix  (32-row tiles)
  const int b = t >> 6, tix = t & 63;
  const float* kt = K + ((size_t)b * NL + tix * KVB) * ND;
  const float* vt = V + ((size_t)b * NL + tix * KVB) * ND;
  unsigned char* kd = ws + WS_K + (size_t)t * TILE_BYTES;
  unsigned char* vd = ws + WS_V + (size_t)t * TILE_BYTES;
#pragma unroll
  for (int it = 0; it < 8; ++it) {
    int idx = it * 128 + threadIdx.x;
    int row = idx >> 5, u = idx & 31, f = u * 8;
    const float4* kp = (const float4*)(kt + (size_t)row * ND + f);
    int kb = (row * 512 + f * 2) ^ ((row & 7) << 4);
    *(short8*)(kd + kb) = cvt8(kp[0], kp[1], 1.0f);
    const float4* vp = (const float4*)(vt + (size_t)row * ND + f);
    int vb = (row >> 2) * 2048 + (u >> 1) * 128 + (row & 3) * 32 + (u & 1) * 16;
    *(short8*)(vd + vb) = cvt8(vp[0], vp[1], 1.0f);
  }
}

// Flash attention fwd: 128 q-rows/block (8 waves), ONE K/V stream feeds both
// 64-row halves -> staged tiles drop 46%, TLP 4 waves/SIMD (LDS-limited
// 2 blocks/CU). launch_bounds(512,2): r17's (512,4) forced VGPR=64 -> scratch
// spill (FETCH 471MB) — the natural allocation is ~112 VGPR, spill-free.
// Swapped-QK in-register softmax per wave, counted-vmcnt pipeline (K 3-buf,
// V 2-buf, raw barriers; V issued before K so K keeps its 2-iter lead).
// Pair 0 spans all 64 kv tiles (-10000-tier tie semantics via LSE combine).
__global__ __launch_bounds__(512, 2)
void attn_fwd(const float* __restrict__ Qg, const unsigned* __restrict__ MBg,
              unsigned char* ws) {
  __shared__ unsigned short Ks[3][KVB * ND];   // 48 KB (also epilogue scratch)
  __shared__ unsigned short Vs[2][KVB * ND];   // 32 KB  => 80 KB total

  const int tid = threadIdx.x;
  const int wv = tid >> 6;      // wave 0..7
  const int lane = tid & 63;
  const int g = lane >> 4;      // 4-lane-group id
  const int cc = lane & 15;     // lane-in-group

  // ---- decode fid -> (b, pair j, chunk c)
  const int fid = blockIdx.x;
  const int b = fid / NCHUNKS_B;
  int rem = fid - b * NCHUNKS_B;
  int j = 0, c = 0, pbase = 0;
  if (rem < 6) {
    j = 0; c = rem; pbase = 0;
  } else {
    rem -= 6; pbase = 6;
    for (j = 1; j < NPAIR; ++j) {
      int ncq = (4 * j + 4 + CHUNK - 1) / CHUNK;
      if (rem < ncq) { c = rem; break; }
      rem -= ncq; pbase += ncq;
    }
  }
  const int qb = j * QB;
  const int nt_s = (j == 0) ? NT_ALL : (4 * j + 4);
  const int t0 = c * CHUNK;
  const int t1 = min(nt_s, t0 + CHUNK);
  unsigned char* pp = ws + WS_P + (size_t)(b * NCHUNKS_B + pbase + c) * PART_BYTES;
  unsigned short* ppA = (unsigned short*)pp;
  float* ppM = (float*)(pp + QB * ND * 2);
  float* ppL = ppM + QB;

  auto stage_K = [&](int tix, int bi) {
    const unsigned char* kg = ws + WS_K + ((size_t)(b * NT_ALL + tix)) * TILE_BYTES;
#pragma unroll
    for (int s = 0; s < 2; ++s) {
      const int seg = wv * 2 + s;  // 16 segs x 1KB; wave-uniform LDS dest
      __builtin_amdgcn_global_load_lds(
          (const __attribute__((address_space(1))) unsigned int*)(kg + seg * 1024 + lane * 16),
          (__attribute__((address_space(3))) unsigned int*)((unsigned char*)&Ks[bi][0] + seg * 1024),
          16, 0, 0);
    }
  };
  auto stage_V = [&](int tix, int bi) {
    const unsigned char* vg = ws + WS_V + ((size_t)(b * NT_ALL + tix)) * TILE_BYTES;
#pragma unroll
    for (int s = 0; s < 2; ++s) {
      const int seg = wv * 2 + s;
      __builtin_amdgcn_global_load_lds(
          (const __attribute__((address_space(1))) unsigned int*)(vg + seg * 1024 + lane * 16),
          (__attribute__((address_space(3))) unsigned int*)((unsigned char*)&Vs[bi][0] + seg * 1024),
          16, 0, 0);
    }
  };

  // ---- Q fragments direct from fp32 (once per block), scaled 1/16
  const float* qp = Qg + ((size_t)b * NL + (qb + 16 * wv + cc)) * ND;
  short8 qf[8];
#pragma unroll
  for (int ch = 0; ch < 8; ++ch) {
    int f = ch * 32 + g * 8;
    float4 a0 = *reinterpret_cast<const float4*>(qp + f);
    float4 a1 = *reinterpret_cast<const float4*>(qp + f + 4);
    qf[ch] = cvt8(a0, a1, 0.0625f);
  }
  const int qg = qb + 16 * wv + cc;  // this lane's q-row (swapped layout)

  f32x4 acc[16];
#pragma unroll
  for (int i = 0; i < 16; ++i) acc[i] = (f32x4){0.f, 0.f, 0.f, 0.f};
  float m_run = -3.0e38f, l_run = 0.f;   // per-lane scalars (row = cc)

  // ---- prologue: retire Q loads (FIFO must contain only DMA), then prime:
  // K(t0), V(t0), K(t0+1)  [V-before-later-K keeps steady counts valid]
  asm volatile("s_waitcnt vmcnt(0)" ::: "memory");
  __builtin_amdgcn_sched_barrier(0);
  stage_K(t0, t0 % 3);
  stage_V(t0, t0 & 1);
  if (t0 + 1 < t1) stage_K(t0 + 1, (t0 + 1) % 3);

  for (int tix = t0; tix < t1; ++tix) {
    // issue V(t+1) then K(t+2): FIFO order preserves K's 2-iter lead
    if (tix + 1 < t1) stage_V(tix + 1, (tix + 1) & 1);
    if (tix + 2 < t1) stage_K(tix + 2, (tix + 2) % 3);
    // counted wait: retire own K(t),V(t); newer prefetch stays in flight
    if (tix + 2 < t1) {
      asm volatile("s_waitcnt vmcnt(6)" ::: "memory");
    } else if (tix + 1 < t1) {
      asm volatile("s_waitcnt vmcnt(4)" ::: "memory");
    } else {
      asm volatile("s_waitcnt vmcnt(0)" ::: "memory");
    }
    __builtin_amdgcn_sched_barrier(0);
    __builtin_amdgcn_s_barrier();   // all waves' tile-t staging visible
    __builtin_amdgcn_sched_barrier(0);

    const int kv0 = tix * KVB;
    const unsigned mb = MBg[b * NT_ALL + tix];  // wave-uniform -> s_load

    // ---- S^T = K Q^T: lane (g,cc) gets S[q=cc][kv0+4g+r] (s0), +16 (s1)
    const char* ksB = (const char*)&Ks[tix % 3][0];
    f32x4 s0 = {0.f, 0.f, 0.f, 0.f}, s1 = {0.f, 0.f, 0.f, 0.f};
    __builtin_amdgcn_s_setprio(1);
#pragma unroll
    for (int ch = 0; ch < 8; ++ch) {
      int cbase = ch * 64 + g * 16;
      int b0 = (cc * 512 + cbase) ^ ((cc & 7) << 4);
      int b1 = ((cc + 16) * 512 + cbase) ^ ((cc & 7) << 4);
      short8 k0 = *reinterpret_cast<const short8*>(ksB + b0);
      short8 k1 = *reinterpret_cast<const short8*>(ksB + b1);
      s0 = __builtin_amdgcn_mfma_f32_16x16x32_bf16(k0, qf[ch], s0, 0, 0, 0);
      s1 = __builtin_amdgcn_mfma_f32_16x16x32_bf16(k1, qf[ch], s1, 0, 0, 0);
    }
    __builtin_amdgcn_s_setprio(0);

    // ---- biases: padding from packed bits + causal, per element
#pragma unroll
    for (int r = 0; r < 4; ++r) {
      int k0i = 4 * g + r, k1i = 16 + 4 * g + r;
      if (!((mb >> k0i) & 1u)) s0[r] -= 10000.f;
      if (!((mb >> k1i) & 1u)) s1[r] -= 10000.f;
      if (kv0 + k0i > qg) s0[r] -= 10000.f;
      if (kv0 + k1i > qg) s1[r] -= 10000.f;
    }

    // ---- online softmax, row-local: in-lane tree + 2 cross-lane rounds
    float rmax = fmaxf(fmaxf(fmaxf(s0[0], s0[1]), fmaxf(s0[2], s0[3])),
                       fmaxf(fmaxf(s1[0], s1[1]), fmaxf(s1[2], s1[3])));
    rmax = fmaxf(rmax, __shfl_xor(rmax, 16));
    rmax = fmaxf(rmax, __shfl_xor(rmax, 32));
    bool grow = (rmax > m_run + 8.f);
    if (__any(grow)) {  // wave-uniform; exact in the LSE combine
      float mn = fmaxf(m_run, rmax);
      float alpha = __expf(m_run - mn);
      m_run = mn;
      l_run *= alpha;   // per-lane partial l; alpha row-uniform -> exact
      f32x4 av;
#pragma unroll
      for (int r = 0; r < 4; ++r) av[r] = __shfl(alpha, 20 * g + r);
#pragma unroll
      for (int i = 0; i < 16; ++i) acc[i] *= av;
    }
    float p0[4], p1[4];
#pragma unroll
    for (int r = 0; r < 4; ++r) {
      p0[r] = __expf(s0[r] - m_run);
      p1[r] = __expf(s1[r] - m_run);
    }
    l_run += (p0[0] + p0[1]) + (p0[2] + p0[3]) +
             (p1[0] + p1[1]) + (p1[2] + p1[3]);

    // ---- build PV A-fragment in-register: pa[j] = P[cc][kv0+8g+j] (bf16)
    unsigned a0, a1, b0w, b1w;
    asm("v_cvt_pk_bf16_f32 %0, %1, %2" : "=v"(a0) : "v"(p0[0]), "v"(p0[1]));
    asm("v_cvt_pk_bf16_f32 %0, %1, %2" : "=v"(a1) : "v"(p0[2]), "v"(p0[3]));
    asm("v_cvt_pk_bf16_f32 %0, %1, %2" : "=v"(b0w) : "v"(p1[0]), "v"(p1[1]));
    asm("v_cvt_pk_bf16_f32 %0, %1, %2" : "=v"(b1w) : "v"(p1[2]), "v"(p1[3]));
    const int srcLo = cc + ((g & 1) << 5);  // lane of source group 2*(g&1)
    const int srcHi = srcLo + 16;           // lane of source group 2*(g&1)+1
    unsigned wa0 = (unsigned)__shfl((int)a0, srcLo);
    unsigned wa1 = (unsigned)__shfl((int)a1, srcLo);
    unsigned wa2 = (unsigned)__shfl((int)a0, srcHi);
    unsigned wa3 = (unsigned)__shfl((int)a1, srcHi);
    unsigned wb0 = (unsigned)__shfl((int)b0w, srcLo);
    unsigned wb1 = (unsigned)__shfl((int)b1w, srcLo);
    unsigned wb2 = (unsigned)__shfl((int)b0w, srcHi);
    unsigned wb3 = (unsigned)__shfl((int)b1w, srcHi);
    const bool hiHalf = (g >= 2);
    u32x4 paw = {hiHalf ? wb0 : wa0, hiHalf ? wb1 : wa1,
                 hiHalf ? wb2 : wa2, hiHalf ? wb3 : wa3};
    short8 pa = __builtin_bit_cast(short8, paw);

    // ---- O += P V: 32 tr-reads issued; counted lgkmcnt(15) overlaps the
    // first MFMA batch with in-flight tr-reads (DS completes in order).
    const unsigned va = (unsigned)(uintptr_t)&Vs[tix & 1][0] + g * 4096 + cc * 8;
    short4v lo[16], hi[16];
#pragma unroll
    for (int ft = 0; ft < 16; ++ft) {
      asm volatile("ds_read_b64_tr_b16 %0, %1 offset:%2"
                   : "=&v"(lo[ft]) : "v"(va), "i"(ft * 128) : "memory");
      asm volatile("ds_read_b64_tr_b16 %0, %1 offset:%2"
                   : "=&v"(hi[ft]) : "v"(va), "i"(ft * 128 + 2048) : "memory");
    }
    asm volatile("s_waitcnt lgkmcnt(15)" ::: "memory");  // >=17 done: ft 0..7
    __builtin_amdgcn_sched_barrier(0);
    __builtin_amdgcn_s_setprio(1);
#pragma unroll
    for (int ft = 0; ft < 8; ++ft) {
      short8 vb = __builtin_shufflevector(lo[ft], hi[ft], 0, 1, 2, 3, 4, 5, 6, 7);
      acc[ft] = __builtin_amdgcn_mfma_f32_16x16x32_bf16(pa, vb, acc[ft], 0, 0, 0);
    }
    __builtin_amdgcn_s_setprio(0);
    asm volatile("s_waitcnt lgkmcnt(0)" ::: "memory");
    __builtin_amdgcn_sched_barrier(0);
    __builtin_amdgcn_s_setprio(1);
#pragma unroll
    for (int ft = 8; ft < 16; ++ft) {
      short8 vb = __builtin_shufflevector(lo[ft], hi[ft], 0, 1, 2, 3, 4, 5, 6, 7);
      acc[ft] = __builtin_amdgcn_mfma_f32_16x16x32_bf16(pa, vb, acc[ft], 0, 0, 0);
    }
    __builtin_amdgcn_s_setprio(0);

    // ---- all waves done reading tile-t buffers before next iteration's
    // issues overwrite them (raw barrier: no counter drain)
    __builtin_amdgcn_sched_barrier(0);
    __builtin_amdgcn_s_barrier();
    __builtin_amdgcn_sched_barrier(0);
  }

  // ---- epilogue: reduce deferred l across the row's 4 lanes
  l_run += __shfl_xor(l_run, 16);
  l_run += __shfl_xor(l_run, 32);
  if (g == 0) {  // lane owns row cc of its wave's 16-row block
    ppM[16 * wv + cc] = m_run;
    ppL[16 * wv + cc] = l_run;
  }

  // transpose acc through LDS in two 64-row half-passes (32 KB of Ks)
  unsigned short* sc = &Ks[0][0];
#pragma unroll
  for (int h = 0; h < 2; ++h) {
    __syncthreads();
    if ((wv >> 2) == h) {
#pragma unroll
      for (int ft = 0; ft < 16; ++ft) {
#pragma unroll
        for (int r = 0; r < 4; ++r) {
          sc[(16 * (wv & 3) + 4 * g + r) * 256 + ft * 16 + cc] = bf16rne(acc[ft][r]);
        }
      }
    }
    __syncthreads();
    const int row = tid >> 3, oct = tid & 7;  // 512 threads: 64 rows x 8 octs
    const ushort8* src = (const ushort8*)(sc + row * 256 + oct * 32);
    ushort8* dst = (ushort8*)(ppA + (size_t)(h * 64 + row) * ND + oct * 32);
#pragma unroll
    for (int kk = 0; kk < 4; ++kk) dst[kk] = src[kk];
  }
}

// Exact log-sum-exp merge of the variable-count partials per (b, pair, half).
__global__ __launch_bounds__(256)
void attn_combine(const unsigned char* __restrict__ ws, float* __restrict__ Og) {
  const int bid = blockIdx.x;  // b(3) | pair j(4) | half(1)
  const int b = bid >> 5;
  const int j = (bid >> 1) & 15;
  const int h = bid & 1;
  const int tid = threadIdx.x;
  const int row = tid >> 2, sub = tid & 3;
  const int grow = h * 64 + row;

  int pbase = 0, nc = 6;
  if (j > 0) {
    pbase = 6;
    for (int jj = 1; jj < j; ++jj) pbase += (4 * jj + 4 + CHUNK - 1) / CHUNK;
    nc = (4 * j + 4 + CHUNK - 1) / CHUNK;
  }
  const unsigned char* p0 = ws + WS_P + (size_t)(b * NCHUNKS_B + pbase) * PART_BYTES;

  float M = -3.0e38f;
  for (int c = 0; c < nc; ++c) {
    M = fmaxf(M, *(const float*)(p0 + (size_t)c * PART_BYTES + QB * ND * 2 + grow * 4));
  }
  float L = 0.f;
  float o[64];
#pragma unroll
  for (int q = 0; q < 64; ++q) o[q] = 0.f;
  for (int c = 0; c < nc; ++c) {
    const unsigned char* pc = p0 + (size_t)c * PART_BYTES;
    float mm = *(const float*)(pc + QB * ND * 2 + grow * 4);
    float ll = *(const float*)(pc + QB * ND * 2 + QB * 4 + grow * 4);
    float s = __expf(mm - M);
    L += ll * s;
    const unsigned short* pa =
        (const unsigned short*)pc + (size_t)grow * ND + sub * 64;
#pragma unroll
    for (int kk = 0; kk < 8; ++kk) {
      ushort8 a = *(const ushort8*)(pa + kk * 8);
#pragma unroll
      for (int q = 0; q < 8; ++q) {
        unsigned u = ((unsigned)a[q]) << 16;
        o[kk * 8 + q] += __builtin_bit_cast(float, u) * s;
      }
    }
  }
  const float invL = 1.0f / L;
  float* op = Og + ((size_t)b * NL + j * QB + grow) * ND + sub * 64;
#pragma unroll
  for (int kk = 0; kk < 16; ++kk) {
    float4 v = {o[kk * 4] * invL, o[kk * 4 + 1] * invL, o[kk * 4 + 2] * invL,
                o[kk * 4 + 3] * invL};
    *(float4*)(op + kk * 4) = v;
  }
}

extern "C" void kernel_launch(void* const* d_in, const int* in_sizes, int n_in,
                              void* d_out, int out_size, void* d_ws, size_t ws_size,
                              hipStream_t stream) {
  (void)in_sizes; (void)n_in; (void)out_size; (void)ws_size;  // ~46.6MB <= 67.6MB proven (r5)
  const float* Q = (const float*)d_in[0];
  const float* K = (const float*)d_in[1];
  const float* V = (const float*)d_in[2];
  const int* M = (const int*)d_in[3];
  unsigned char* ws = (unsigned char*)d_ws;

  mask_pack<<<dim3(1), dim3(512), 0, stream>>>((const unsigned*)M,
                                               (unsigned*)(ws + WS_MB));
  convert_kv<<<dim3(512), dim3(128), 0, stream>>>(K, V, ws);
  attn_fwd<<<dim3(8 * NCHUNKS_B), dim3(512), 0, stream>>>(
      Q, (const unsigned*)(ws + WS_MB), ws);
  attn_combine<<<dim3(256), dim3(256), 0, stream>>>(ws, (float*)d_out);
}

// Round 19
// 107.824 us; speedup vs baseline: 2.2801x; 1.0452x over previous
//
#include <hip/hip_runtime.h>
#include <stdint.h>

#define NL 2048
#define ND 256
#define KVB 32
#define QB 64
#define NQT 32                      // 64-row q-tiles per batch
#define NT_ALL (NL / KVB)           // 64 kv tiles per batch
#define CHUNK 10                    // kv tiles per block -> 125 chunks/batch, grid 1000
#define NCHUNKS_B 125               // 7 (qt=0 spans all 64) + sum_{qt=1..31} ceil((2qt+2)/10)
#define TILE_BYTES (KVB * ND * 2)   // 16 KB image per kv tile
#define IMG (8 * NT_ALL * TILE_BYTES)
#define WS_MB 256                   // 512 u32 packed mask bits (2 KB)
#define WS_K (WS_MB + 2048)
#define WS_V (WS_K + IMG)           // V stored TRANSPOSED per tile: [d=256][kv=32] bf16
#define WS_P (WS_V + IMG)
#define PART_BYTES (QB * ND * 2 + QB * 8)  // bf16 acc + fp32 m,l = 33280

typedef __attribute__((ext_vector_type(8))) short short8;
typedef __attribute__((ext_vector_type(4))) float f32x4;
typedef __attribute__((ext_vector_type(4))) unsigned int u32x4;
typedef __attribute__((ext_vector_type(8))) unsigned short ushort8;

__device__ __forceinline__ unsigned short bf16rne(float x) {
  unsigned u = __builtin_bit_cast(unsigned, x);
  u += 0x7FFFu + ((u >> 16) & 1u);
  return (unsigned short)(u >> 16);
}

__device__ __forceinline__ short8 cvt8(float4 a, float4 b, float scale) {
  short8 v;
  v[0] = (short)bf16rne(a.x * scale);
  v[1] = (short)bf16rne(a.y * scale);
  v[2] = (short)bf16rne(a.z * scale);
  v[3] = (short)bf16rne(a.w * scale);
  v[4] = (short)bf16rne(b.x * scale);
  v[5] = (short)bf16rne(b.y * scale);
  v[6] = (short)bf16rne(b.z * scale);
  v[7] = (short)bf16rne(b.w * scale);
  return v;
}

// Detect mask storage (int32 words vs byte bools) and pack one 32-bit mask
// word per kv-tile: bit k = mask[b, tix*32+k]. 1 block x 512 threads.
__global__ __launch_bounds__(512)
void mask_pack(const unsigned* __restrict__ M, unsigned* __restrict__ MB) {
  __shared__ int badS;
  if (threadIdx.x == 0) badS = 0;
  __syncthreads();
  bool bad = false;
  for (int i = threadIdx.x; i < 4096; i += 512)
    if (M[i] > 1u) bad = true;
  if (__any(bad) && (threadIdx.x & 63) == 0) badS = 1;
  __syncthreads();
  const int byteMode = badS;
  const int i = threadIdx.x;  // kv-tile id = b*64 + tix
  unsigned m = 0;
  for (int j = 0; j < 32; ++j) {
    int mv = byteMode ? (int)((const unsigned char*)M)[i * 32 + j] : (int)M[i * 32 + j];
    m |= (mv ? 1u : 0u) << j;
  }
  MB[i] = m;
}

// One-shot K,V fp32->bf16 conversion. K stored as XOR-swizzled LDS tile
// images; V stored TRANSPOSED per tile ([d][kv] bf16) so the PV B-fragment
// is ONE contiguous ds_read_b128 (conflict-free by construction).
__global__ __launch_bounds__(128)
void convert_kv(const float* __restrict__ K, const float* __restrict__ V,
                unsigned char* __restrict__ ws) {
  const int t = blockIdx.x;  // b*64 + tix  (32-row tiles)
  const int b = t >> 6, tix = t & 63;
  const float* kt = K + ((size_t)b * NL + tix * KVB) * ND;
  const float* vt = V + ((size_t)b * NL + tix * KVB) * ND;
  unsigned char* kd = ws + WS_K + (size_t)t * TILE_BYTES;
  unsigned char* vd = ws + WS_V + (size_t)t * TILE_BYTES;
#pragma unroll
  for (int it = 0; it < 8; ++it) {
    int idx = it * 128 + threadIdx.x;
    int row = idx >> 5, u = idx & 31, f = u * 8;
    const float4* kp = (const float4*)(kt + (size_t)row * ND + f);
    int kb = (row * 512 + f * 2) ^ ((row & 7) << 4);
    *(short8*)(kd + kb) = cvt8(kp[0], kp[1], 1.0f);
    const float4* vp = (const float4*)(vt + (size_t)row * ND + f);
    short8 v8 = cvt8(vp[0], vp[1], 1.0f);
#pragma unroll
    for (int j = 0; j < 8; ++j) {  // V^T: byte off = d*64 + kv*2
      *(unsigned short*)(vd + (size_t)(f + j) * 64 + row * 2) = (unsigned short)v8[j];
    }
  }
}

// Flash attention fwd: swapped-QK in-register softmax + counted-vmcnt
// pipeline (K 3-buf, V 2-buf, 80 KB LDS, raw barriers). PV B-fragments are
// single ds_read_b128 from the V^T tile (no tr-reads, no shuffles).
// Defer-max; deferred l-reduce. qt=0 spans all 64 kv tiles (-10000-tier
// tie semantics via the LSE combine).
__global__ __launch_bounds__(256, 2)
void attn_fwd(const float* __restrict__ Qg, const unsigned* __restrict__ MBg,
              unsigned char* ws) {
  __shared__ unsigned short Ks[3][KVB * ND];   // 48 KB (also epilogue scratch)
  __shared__ unsigned short Vs[2][KVB * ND];   // 32 KB (V^T tiles)

  const int tid = threadIdx.x;
  const int wv = tid >> 6;      // wave 0..3
  const int lane = tid & 63;
  const int g = lane >> 4;      // 4-lane-group id
  const int cc = lane & 15;     // lane-in-group

  // ---- decode fid -> (b, qt, c)
  const int fid = blockIdx.x;
  const int b = fid / NCHUNKS_B;
  int rem = fid - b * NCHUNKS_B;
  int qt = 0, c = 0, pbase = 0;
  if (rem < 7) {
    qt = 0; c = rem; pbase = 0;
  } else {
    rem -= 7; pbase = 7;
    for (qt = 1; qt < NQT; ++qt) {
      int ncq = (2 * qt + 2 + CHUNK - 1) / CHUNK;
      if (rem < ncq) { c = rem; break; }
      rem -= ncq; pbase += ncq;
    }
  }
  const int qb = qt * QB;
  const int nt_s = (qt == 0) ? NT_ALL : (2 * qt + 2);
  const int t0 = c * CHUNK;
  const int t1 = min(nt_s, t0 + CHUNK);
  unsigned char* pp = ws + WS_P + (size_t)(b * NCHUNKS_B + pbase + c) * PART_BYTES;
  unsigned short* ppA = (unsigned short*)pp;
  float* ppM = (float*)(pp + QB * ND * 2);
  float* ppL = ppM + QB;

  auto stage_K = [&](int tix, int bi) {
    const unsigned char* kg = ws + WS_K + ((size_t)(b * NT_ALL + tix)) * TILE_BYTES;
#pragma unroll
    for (int s = 0; s < 4; ++s) {
      const int seg = wv * 4 + s;  // wave-uniform LDS dest; per-lane global src
      __builtin_amdgcn_global_load_lds(
          (const __attribute__((address_space(1))) unsigned int*)(kg + seg * 1024 + lane * 16),
          (__attribute__((address_space(3))) unsigned int*)((unsigned char*)&Ks[bi][0] + seg * 1024),
          16, 0, 0);
    }
  };
  auto stage_V = [&](int tix, int bi) {
    const unsigned char* vg = ws + WS_V + ((size_t)(b * NT_ALL + tix)) * TILE_BYTES;
#pragma unroll
    for (int s = 0; s < 4; ++s) {
      const int seg = wv * 4 + s;
      __builtin_amdgcn_global_load_lds(
          (const __attribute__((address_space(1))) unsigned int*)(vg + seg * 1024 + lane * 16),
          (__attribute__((address_space(3))) unsigned int*)((unsigned char*)&Vs[bi][0] + seg * 1024),
          16, 0, 0);
    }
  };

  // ---- Q fragments direct from fp32 (once per block), scaled 1/16
  const float* qp = Qg + ((size_t)b * NL + (qb + 16 * wv + cc)) * ND;
  short8 qf[8];
#pragma unroll
  for (int ch = 0; ch < 8; ++ch) {
    int f = ch * 32 + g * 8;
    float4 a0 = *reinterpret_cast<const float4*>(qp + f);
    float4 a1 = *reinterpret_cast<const float4*>(qp + f + 4);
    qf[ch] = cvt8(a0, a1, 0.0625f);
  }
  const int qg = qb + 16 * wv + cc;  // this lane's q-row (swapped layout)

  f32x4 acc[16];
#pragma unroll
  for (int i = 0; i < 16; ++i) acc[i] = (f32x4){0.f, 0.f, 0.f, 0.f};
  float m_run = -3.0e38f, l_run = 0.f;   // per-lane scalars (row = cc)

  // ---- prologue: retire Q loads (FIFO must contain only DMA), then prime
  // the pipe: K(t0), K(t0+1) [both OLDER than V(t0) so steady counts hold].
  asm volatile("s_waitcnt vmcnt(0)" ::: "memory");
  __builtin_amdgcn_sched_barrier(0);
  stage_K(t0, t0 % 3);
  if (t0 + 1 < t1) stage_K(t0 + 1, (t0 + 1) % 3);
  stage_V(t0, t0 & 1);

  for (int tix = t0; tix < t1; ++tix) {
    // issue next K/V into buffers freed by the barrier ending the previous
    // iteration (K 2-deep, V 1-deep prefetch)
    if (tix + 2 < t1) stage_K(tix + 2, (tix + 2) % 3);
    if (tix + 1 < t1) stage_V(tix + 1, (tix + 1) & 1);
    // counted wait: retire own K(t),V(t); newer prefetch stays in flight
    if (tix + 2 < t1) {
      asm volatile("s_waitcnt vmcnt(8)" ::: "memory");
    } else if (tix + 1 < t1) {
      asm volatile("s_waitcnt vmcnt(4)" ::: "memory");
    } else {
      asm volatile("s_waitcnt vmcnt(0)" ::: "memory");
    }
    __builtin_amdgcn_sched_barrier(0);
    __builtin_amdgcn_s_barrier();   // all waves' tile-t staging visible
    __builtin_amdgcn_sched_barrier(0);

    const int kv0 = tix * KVB;
    const unsigned mb = MBg[b * NT_ALL + tix];  // wave-uniform -> s_load

    // ---- S^T = K Q^T: lane (g,cc) gets S[q=cc][kv0+4g+r] (s0), +16 (s1)
    const char* ksB = (const char*)&Ks[tix % 3][0];
    f32x4 s0 = {0.f, 0.f, 0.f, 0.f}, s1 = {0.f, 0.f, 0.f, 0.f};
    __builtin_amdgcn_s_setprio(1);
#pragma unroll
    for (int ch = 0; ch < 8; ++ch) {
      int cbase = ch * 64 + g * 16;
      int b0 = (cc * 512 + cbase) ^ ((cc & 7) << 4);
      int b1 = ((cc + 16) * 512 + cbase) ^ ((cc & 7) << 4);
      short8 k0 = *reinterpret_cast<const short8*>(ksB + b0);
      short8 k1 = *reinterpret_cast<const short8*>(ksB + b1);
      s0 = __builtin_amdgcn_mfma_f32_16x16x32_bf16(k0, qf[ch], s0, 0, 0, 0);
      s1 = __builtin_amdgcn_mfma_f32_16x16x32_bf16(k1, qf[ch], s1, 0, 0, 0);
    }
    __builtin_amdgcn_s_setprio(0);

    // ---- biases: padding from packed bits + causal, per element
#pragma unroll
    for (int r = 0; r < 4; ++r) {
      int k0i = 4 * g + r, k1i = 16 + 4 * g + r;
      if (!((mb >> k0i) & 1u)) s0[r] -= 10000.f;
      if (!((mb >> k1i) & 1u)) s1[r] -= 10000.f;
      if (kv0 + k0i > qg) s0[r] -= 10000.f;
      if (kv0 + k1i > qg) s1[r] -= 10000.f;
    }

    // ---- online softmax, row-local: in-lane tree + 2 cross-lane rounds
    float rmax = fmaxf(fmaxf(fmaxf(s0[0], s0[1]), fmaxf(s0[2], s0[3])),
                       fmaxf(fmaxf(s1[0], s1[1]), fmaxf(s1[2], s1[3])));
    rmax = fmaxf(rmax, __shfl_xor(rmax, 16));
    rmax = fmaxf(rmax, __shfl_xor(rmax, 32));
    bool grow = (rmax > m_run + 8.f);
    if (__any(grow)) {  // wave-uniform; exact in the LSE combine
      float mn = fmaxf(m_run, rmax);
      float alpha = __expf(m_run - mn);
      m_run = mn;
      l_run *= alpha;   // per-lane partial l; alpha row-uniform -> exact
      f32x4 av;
#pragma unroll
      for (int r = 0; r < 4; ++r) av[r] = __shfl(alpha, 20 * g + r);
#pragma unroll
      for (int i = 0; i < 16; ++i) acc[i] *= av;
    }
    float p0[4], p1[4];
#pragma unroll
    for (int r = 0; r < 4; ++r) {
      p0[r] = __expf(s0[r] - m_run);
      p1[r] = __expf(s1[r] - m_run);
    }
    // deferred l: accumulate per-lane partial only (reduced in epilogue)
    l_run += (p0[0] + p0[1]) + (p0[2] + p0[3]) +
             (p1[0] + p1[1]) + (p1[2] + p1[3]);

    // ---- build PV A-fragment in-register: pa[j] = P[cc][kv0+8g+j] (bf16)
    unsigned a0, a1, b0w, b1w;
    asm("v_cvt_pk_bf16_f32 %0, %1, %2" : "=v"(a0) : "v"(p0[0]), "v"(p0[1]));
    asm("v_cvt_pk_bf16_f32 %0, %1, %2" : "=v"(a1) : "v"(p0[2]), "v"(p0[3]));
    asm("v_cvt_pk_bf16_f32 %0, %1, %2" : "=v"(b0w) : "v"(p1[0]), "v"(p1[1]));
    asm("v_cvt_pk_bf16_f32 %0, %1, %2" : "=v"(b1w) : "v"(p1[2]), "v"(p1[3]));
    const int srcLo = cc + ((g & 1) << 5);  // lane of source group 2*(g&1)
    const int srcHi = srcLo + 16;           // lane of source group 2*(g&1)+1
    unsigned wa0 = (unsigned)__shfl((int)a0, srcLo);
    unsigned wa1 = (unsigned)__shfl((int)a1, srcLo);
    unsigned wa2 = (unsigned)__shfl((int)a0, srcHi);
    unsigned wa3 = (unsigned)__shfl((int)a1, srcHi);
    unsigned wb0 = (unsigned)__shfl((int)b0w, srcLo);
    unsigned wb1 = (unsigned)__shfl((int)b1w, srcLo);
    unsigned wb2 = (unsigned)__shfl((int)b0w, srcHi);
    unsigned wb3 = (unsigned)__shfl((int)b1w, srcHi);
    const bool hiHalf = (g >= 2);
    u32x4 paw = {hiHalf ? wb0 : wa0, hiHalf ? wb1 : wa1,
                 hiHalf ? wb2 : wa2, hiHalf ? wb3 : wa3};
    short8 pa = __builtin_bit_cast(short8, paw);

    // ---- O += P V: B-fragment = ONE ds_read_b128 from V^T tile per ft.
    // addr = (ft*16+cc)*64 + g*16: all 8 bank-groups covered, 8 rows each
    // -> structural-floor LDS cost, no swizzle. Counted lgkmcnt(8) overlaps
    // the first MFMA batch with the second read batch (DS in-order).
    const unsigned va = (unsigned)(uintptr_t)&Vs[tix & 1][0] + cc * 64 + g * 16;
    short8 vb[16];
#pragma unroll
    for (int ft = 0; ft < 16; ++ft) {
      asm volatile("ds_read_b128 %0, %1 offset:%2"
                   : "=&v"(vb[ft]) : "v"(va), "i"(ft * 1024) : "memory");
    }
    asm volatile("s_waitcnt lgkmcnt(8)" ::: "memory");  // ft 0..7 done
    __builtin_amdgcn_sched_barrier(0);
    __builtin_amdgcn_s_setprio(1);
#pragma unroll
    for (int ft = 0; ft < 8; ++ft) {
      acc[ft] = __builtin_amdgcn_mfma_f32_16x16x32_bf16(pa, vb[ft], acc[ft], 0, 0, 0);
    }
    __builtin_amdgcn_s_setprio(0);
    asm volatile("s_waitcnt lgkmcnt(0)" ::: "memory");
    __builtin_amdgcn_sched_barrier(0);
    __builtin_amdgcn_s_setprio(1);
#pragma unroll
    for (int ft = 8; ft < 16; ++ft) {
      acc[ft] = __builtin_amdgcn_mfma_f32_16x16x32_bf16(pa, vb[ft], acc[ft], 0, 0, 0);
    }
    __builtin_amdgcn_s_setprio(0);

    // ---- all waves done reading tile-t buffers before next iteration's
    // issues overwrite them (raw barrier: no counter drain)
    __builtin_amdgcn_sched_barrier(0);
    __builtin_amdgcn_s_barrier();
    __builtin_amdgcn_sched_barrier(0);
  }

  // ---- epilogue: reduce deferred l across the row's 4 lanes
  l_run += __shfl_xor(l_run, 16);
  l_run += __shfl_xor(l_run, 32);

  // transpose acc through LDS (reuse Ks, 48 KB available)
  unsigned short* sc = &Ks[0][0];
#pragma unroll
  for (int ft = 0; ft < 16; ++ft) {
#pragma unroll
    for (int r = 0; r < 4; ++r) {
      sc[(16 * wv + 4 * g + r) * 256 + ft * 16 + cc] = bf16rne(acc[ft][r]);
    }
  }
  if (g == 0) {  // lane owns row cc: one writer per row
    ppM[16 * wv + cc] = m_run;
    ppL[16 * wv + cc] = l_run;
  }
  __syncthreads();
  {
    const int row = tid >> 2, q4 = tid & 3;
    const unsigned short* srow = sc + row * 256 + q4 * 64;
#pragma unroll
    for (int kk = 0; kk < 8; ++kk) {
      *(ushort8*)(ppA + (size_t)row * ND + q4 * 64 + kk * 8) =
          *(const ushort8*)(srow + kk * 8);
    }
  }
}

// Exact log-sum-exp merge of the variable-count partials per (b, q-tile).
__global__ __launch_bounds__(256)
void attn_combine(const unsigned char* __restrict__ ws, float* __restrict__ Og) {
  const int bid = blockIdx.x;  // b*32 + qt
  const int b = bid >> 5, qt = bid & 31;
  const int tid = threadIdx.x;
  const int row = tid >> 2, sub = tid & 3;

  int pbase = 0, nc = 7;
  if (qt > 0) {
    pbase = 7;
    for (int j = 1; j < qt; ++j) pbase += (2 * j + 2 + CHUNK - 1) / CHUNK;
    nc = (2 * qt + 2 + CHUNK - 1) / CHUNK;
  }
  const unsigned char* p0 = ws + WS_P + (size_t)(b * NCHUNKS_B + pbase) * PART_BYTES;

  float M = -3.0e38f;
  for (int c = 0; c < nc; ++c) {
    M = fmaxf(M, *(const float*)(p0 + (size_t)c * PART_BYTES + QB * ND * 2 + row * 4));
  }
  float L = 0.f;
  float o[64];
#pragma unroll
  for (int j = 0; j < 64; ++j) o[j] = 0.f;
  for (int c = 0; c < nc; ++c) {
    const unsigned char* pc = p0 + (size_t)c * PART_BYTES;
    float mm = *(const float*)(pc + QB * ND * 2 + row * 4);
    float ll = *(const float*)(pc + QB * ND * 2 + QB * 4 + row * 4);
    float s = __expf(mm - M);
    L += ll * s;
    const unsigned short* pa =
        (const unsigned short*)pc + (size_t)row * ND + sub * 64;
#pragma unroll
    for (int kk = 0; kk < 8; ++kk) {
      ushort8 a = *(const ushort8*)(pa + kk * 8);
#pragma unroll
      for (int j = 0; j < 8; ++j) {
        unsigned u = ((unsigned)a[j]) << 16;
        o[kk * 8 + j] += __builtin_bit_cast(float, u) * s;
      }
    }
  }
  const float invL = 1.0f / L;
  float* op = Og + ((size_t)b * NL + qt * QB + row) * ND + sub * 64;
#pragma unroll
  for (int kk = 0; kk < 16; ++kk) {
    float4 v = {o[kk * 4] * invL, o[kk * 4 + 1] * invL, o[kk * 4 + 2] * invL,
                o[kk * 4 + 3] * invL};
    *(float4*)(op + kk * 4) = v;
  }
}

extern "C" void kernel_launch(void* const* d_in, const int* in_sizes, int n_in,
                              void* d_out, int out_size, void* d_ws, size_t ws_size,
                              hipStream_t stream) {
  (void)in_sizes; (void)n_in; (void)out_size; (void)ws_size;  // ~49.3MB <= 67.6MB proven (r5)
  const float* Q = (const float*)d_in[0];
  const float* K = (const float*)d_in[1];
  const float* V = (const float*)d_in[2];
  const int* M = (const int*)d_in[3];
  unsigned char* ws = (unsigned char*)d_ws;

  mask_pack<<<dim3(1), dim3(512), 0, stream>>>((const unsigned*)M,
                                               (unsigned*)(ws + WS_MB));
  convert_kv<<<dim3(512), dim3(128), 0, stream>>>(K, V, ws);
  attn_fwd<<<dim3(8 * NCHUNKS_B), dim3(256), 0, stream>>>(
      Q, (const unsigned*)(ws + WS_MB), ws);
  attn_combine<<<dim3(256), dim3(256), 0, stream>>>(ws, (float*)d_out);
}

// Round 20
// 100.688 us; speedup vs baseline: 2.4417x; 1.0709x over previous
//
#include <hip/hip_runtime.h>
#include <stdint.h>

#define NL 2048
#define ND 256
#define KVB 32
#define QB 64
#define NQT 32                      // 64-row q-tiles per batch
#define NT_ALL (NL / KVB)           // 64 kv tiles per batch
#define CHUNK 10                    // kv tiles per block -> 125 chunks/batch, grid 1000
#define NCHUNKS_B 125               // 7 (qt=0 spans all 64) + sum_{qt=1..31} ceil((2qt+2)/10)
#define TILE_BYTES (KVB * ND * 2)   // 16 KB image per kv tile
#define IMG (8 * NT_ALL * TILE_BYTES)
#define WS_MB 256                   // 512 u32 packed mask bits (2 KB)
#define WS_K (WS_MB + 2048)
#define WS_V (WS_K + IMG)           // V stored TRANSPOSED per tile: [d=256][kv=32] bf16
#define WS_P (WS_V + IMG)
#define PART_BYTES (QB * ND * 2 + QB * 8)  // bf16 acc + fp32 m,l = 33280

typedef __attribute__((ext_vector_type(8))) short short8;
typedef __attribute__((ext_vector_type(4))) float f32x4;
typedef __attribute__((ext_vector_type(4))) unsigned int u32x4;
typedef __attribute__((ext_vector_type(8))) unsigned short ushort8;

__device__ __forceinline__ unsigned short bf16rne(float x) {
  unsigned u = __builtin_bit_cast(unsigned, x);
  u += 0x7FFFu + ((u >> 16) & 1u);
  return (unsigned short)(u >> 16);
}

__device__ __forceinline__ short8 cvt8(float4 a, float4 b, float scale) {
  short8 v;
  v[0] = (short)bf16rne(a.x * scale);
  v[1] = (short)bf16rne(a.y * scale);
  v[2] = (short)bf16rne(a.z * scale);
  v[3] = (short)bf16rne(a.w * scale);
  v[4] = (short)bf16rne(b.x * scale);
  v[5] = (short)bf16rne(b.y * scale);
  v[6] = (short)bf16rne(b.z * scale);
  v[7] = (short)bf16rne(b.w * scale);
  return v;
}

// One-shot K,V fp32->bf16 conversion. K stored as XOR-swizzled LDS tile
// images; V stored TRANSPOSED per tile ([d][kv] bf16) so the PV B-fragment
// is ONE contiguous ds_read_b128. Block 512 packs the padding mask instead
// (fused mask_pack: one fewer dispatch).
__global__ __launch_bounds__(128)
void convert_kv(const float* __restrict__ K, const float* __restrict__ V,
                const unsigned* __restrict__ M, unsigned char* __restrict__ ws) {
  if (blockIdx.x == 512) {
    // ---- mask packing: detect storage (int32 words vs byte bools), then
    // pack one 32-bit word per kv-tile: bit k = mask[b, tix*32+k].
    __shared__ int badS;
    if (threadIdx.x == 0) badS = 0;
    __syncthreads();
    bool bad = false;
    for (int i = threadIdx.x; i < 4096; i += 128)
      if (M[i] > 1u) bad = true;
    if (__any(bad) && (threadIdx.x & 63) == 0) badS = 1;
    __syncthreads();
    const int byteMode = badS;
    unsigned* MB = (unsigned*)(ws + WS_MB);
    for (int t = threadIdx.x; t < 512; t += 128) {
      unsigned m = 0;
      for (int j = 0; j < 32; ++j) {
        int mv = byteMode ? (int)((const unsigned char*)M)[t * 32 + j]
                          : (int)M[t * 32 + j];
        m |= (mv ? 1u : 0u) << j;
      }
      MB[t] = m;
    }
    return;
  }
  const int t = blockIdx.x;  // b*64 + tix  (32-row tiles)
  const int b = t >> 6, tix = t & 63;
  const float* kt = K + ((size_t)b * NL + tix * KVB) * ND;
  const float* vt = V + ((size_t)b * NL + tix * KVB) * ND;
  unsigned char* kd = ws + WS_K + (size_t)t * TILE_BYTES;
  unsigned char* vd = ws + WS_V + (size_t)t * TILE_BYTES;
#pragma unroll
  for (int it = 0; it < 8; ++it) {
    int idx = it * 128 + threadIdx.x;
    int row = idx >> 5, u = idx & 31, f = u * 8;
    const float4* kp = (const float4*)(kt + (size_t)row * ND + f);
    int kb = (row * 512 + f * 2) ^ ((row & 7) << 4);
    *(short8*)(kd + kb) = cvt8(kp[0], kp[1], 1.0f);
    const float4* vp = (const float4*)(vt + (size_t)row * ND + f);
    short8 v8 = cvt8(vp[0], vp[1], 1.0f);
#pragma unroll
    for (int j = 0; j < 8; ++j) {  // V^T: byte off = d*64 + kv*2
      *(unsigned short*)(vd + (size_t)(f + j) * 64 + row * 2) = (unsigned short)v8[j];
    }
  }
}

// Flash attention fwd: swapped-QK in-register softmax + counted-vmcnt
// pipeline (K 3-buf, V 2-buf, 80 KB LDS, raw barriers). PV B-fragments are
// single ds_read_b128 from the V^T tile. Defer-max; deferred l-reduce.
// qt=0 spans all 64 kv tiles (-10000-tier tie semantics via LSE combine).
// [FROZEN from r19: fwd is at an LDS-throughput/latency equilibrium.]
__global__ __launch_bounds__(256, 2)
void attn_fwd(const float* __restrict__ Qg, const unsigned* __restrict__ MBg,
              unsigned char* ws) {
  __shared__ unsigned short Ks[3][KVB * ND];   // 48 KB (also epilogue scratch)
  __shared__ unsigned short Vs[2][KVB * ND];   // 32 KB (V^T tiles)

  const int tid = threadIdx.x;
  const int wv = tid >> 6;      // wave 0..3
  const int lane = tid & 63;
  const int g = lane >> 4;      // 4-lane-group id
  const int cc = lane & 15;     // lane-in-group

  // ---- decode fid -> (b, qt, c)
  const int fid = blockIdx.x;
  const int b = fid / NCHUNKS_B;
  int rem = fid - b * NCHUNKS_B;
  int qt = 0, c = 0, pbase = 0;
  if (rem < 7) {
    qt = 0; c = rem; pbase = 0;
  } else {
    rem -= 7; pbase = 7;
    for (qt = 1; qt < NQT; ++qt) {
      int ncq = (2 * qt + 2 + CHUNK - 1) / CHUNK;
      if (rem < ncq) { c = rem; break; }
      rem -= ncq; pbase += ncq;
    }
  }
  const int qb = qt * QB;
  const int nt_s = (qt == 0) ? NT_ALL : (2 * qt + 2);
  const int t0 = c * CHUNK;
  const int t1 = min(nt_s, t0 + CHUNK);
  unsigned char* pp = ws + WS_P + (size_t)(b * NCHUNKS_B + pbase + c) * PART_BYTES;
  unsigned short* ppA = (unsigned short*)pp;
  float* ppM = (float*)(pp + QB * ND * 2);
  float* ppL = ppM + QB;

  auto stage_K = [&](int tix, int bi) {
    const unsigned char* kg = ws + WS_K + ((size_t)(b * NT_ALL + tix)) * TILE_BYTES;
#pragma unroll
    for (int s = 0; s < 4; ++s) {
      const int seg = wv * 4 + s;  // wave-uniform LDS dest; per-lane global src
      __builtin_amdgcn_global_load_lds(
          (const __attribute__((address_space(1))) unsigned int*)(kg + seg * 1024 + lane * 16),
          (__attribute__((address_space(3))) unsigned int*)((unsigned char*)&Ks[bi][0] + seg * 1024),
          16, 0, 0);
    }
  };
  auto stage_V = [&](int tix, int bi) {
    const unsigned char* vg = ws + WS_V + ((size_t)(b * NT_ALL + tix)) * TILE_BYTES;
#pragma unroll
    for (int s = 0; s < 4; ++s) {
      const int seg = wv * 4 + s;
      __builtin_amdgcn_global_load_lds(
          (const __attribute__((address_space(1))) unsigned int*)(vg + seg * 1024 + lane * 16),
          (__attribute__((address_space(3))) unsigned int*)((unsigned char*)&Vs[bi][0] + seg * 1024),
          16, 0, 0);
    }
  };

  // ---- Q fragments direct from fp32 (once per block), scaled 1/16
  const float* qp = Qg + ((size_t)b * NL + (qb + 16 * wv + cc)) * ND;
  short8 qf[8];
#pragma unroll
  for (int ch = 0; ch < 8; ++ch) {
    int f = ch * 32 + g * 8;
    float4 a0 = *reinterpret_cast<const float4*>(qp + f);
    float4 a1 = *reinterpret_cast<const float4*>(qp + f + 4);
    qf[ch] = cvt8(a0, a1, 0.0625f);
  }
  const int qg = qb + 16 * wv + cc;  // this lane's q-row (swapped layout)

  f32x4 acc[16];
#pragma unroll
  for (int i = 0; i < 16; ++i) acc[i] = (f32x4){0.f, 0.f, 0.f, 0.f};
  float m_run = -3.0e38f, l_run = 0.f;   // per-lane scalars (row = cc)

  // ---- prologue: retire Q loads (FIFO must contain only DMA), then prime
  // the pipe: K(t0), K(t0+1) [both OLDER than V(t0) so steady counts hold].
  asm volatile("s_waitcnt vmcnt(0)" ::: "memory");
  __builtin_amdgcn_sched_barrier(0);
  stage_K(t0, t0 % 3);
  if (t0 + 1 < t1) stage_K(t0 + 1, (t0 + 1) % 3);
  stage_V(t0, t0 & 1);

  for (int tix = t0; tix < t1; ++tix) {
    // issue next K/V into buffers freed by the barrier ending the previous
    // iteration (K 2-deep, V 1-deep prefetch)
    if (tix + 2 < t1) stage_K(tix + 2, (tix + 2) % 3);
    if (tix + 1 < t1) stage_V(tix + 1, (tix + 1) & 1);
    // counted wait: retire own K(t),V(t); newer prefetch stays in flight
    if (tix + 2 < t1) {
      asm volatile("s_waitcnt vmcnt(8)" ::: "memory");
    } else if (tix + 1 < t1) {
      asm volatile("s_waitcnt vmcnt(4)" ::: "memory");
    } else {
      asm volatile("s_waitcnt vmcnt(0)" ::: "memory");
    }
    __builtin_amdgcn_sched_barrier(0);
    __builtin_amdgcn_s_barrier();   // all waves' tile-t staging visible
    __builtin_amdgcn_sched_barrier(0);

    const int kv0 = tix * KVB;
    const unsigned mb = MBg[b * NT_ALL + tix];  // wave-uniform -> s_load

    // ---- S^T = K Q^T: lane (g,cc) gets S[q=cc][kv0+4g+r] (s0), +16 (s1)
    const char* ksB = (const char*)&Ks[tix % 3][0];
    f32x4 s0 = {0.f, 0.f, 0.f, 0.f}, s1 = {0.f, 0.f, 0.f, 0.f};
    __builtin_amdgcn_s_setprio(1);
#pragma unroll
    for (int ch = 0; ch < 8; ++ch) {
      int cbase = ch * 64 + g * 16;
      int b0 = (cc * 512 + cbase) ^ ((cc & 7) << 4);
      int b1 = ((cc + 16) * 512 + cbase) ^ ((cc & 7) << 4);
      short8 k0 = *reinterpret_cast<const short8*>(ksB + b0);
      short8 k1 = *reinterpret_cast<const short8*>(ksB + b1);
      s0 = __builtin_amdgcn_mfma_f32_16x16x32_bf16(k0, qf[ch], s0, 0, 0, 0);
      s1 = __builtin_amdgcn_mfma_f32_16x16x32_bf16(k1, qf[ch], s1, 0, 0, 0);
    }
    __builtin_amdgcn_s_setprio(0);

    // ---- biases: padding from packed bits + causal, per element
#pragma unroll
    for (int r = 0; r < 4; ++r) {
      int k0i = 4 * g + r, k1i = 16 + 4 * g + r;
      if (!((mb >> k0i) & 1u)) s0[r] -= 10000.f;
      if (!((mb >> k1i) & 1u)) s1[r] -= 10000.f;
      if (kv0 + k0i > qg) s0[r] -= 10000.f;
      if (kv0 + k1i > qg) s1[r] -= 10000.f;
    }

    // ---- online softmax, row-local: in-lane tree + 2 cross-lane rounds
    float rmax = fmaxf(fmaxf(fmaxf(s0[0], s0[1]), fmaxf(s0[2], s0[3])),
                       fmaxf(fmaxf(s1[0], s1[1]), fmaxf(s1[2], s1[3])));
    rmax = fmaxf(rmax, __shfl_xor(rmax, 16));
    rmax = fmaxf(rmax, __shfl_xor(rmax, 32));
    bool grow = (rmax > m_run + 8.f);
    if (__any(grow)) {  // wave-uniform; exact in the LSE combine
      float mn = fmaxf(m_run, rmax);
      float alpha = __expf(m_run - mn);
      m_run = mn;
      l_run *= alpha;   // per-lane partial l; alpha row-uniform -> exact
      f32x4 av;
#pragma unroll
      for (int r = 0; r < 4; ++r) av[r] = __shfl(alpha, 20 * g + r);
#pragma unroll
      for (int i = 0; i < 16; ++i) acc[i] *= av;
    }
    float p0[4], p1[4];
#pragma unroll
    for (int r = 0; r < 4; ++r) {
      p0[r] = __expf(s0[r] - m_run);
      p1[r] = __expf(s1[r] - m_run);
    }
    // deferred l: accumulate per-lane partial only (reduced in epilogue)
    l_run += (p0[0] + p0[1]) + (p0[2] + p0[3]) +
             (p1[0] + p1[1]) + (p1[2] + p1[3]);

    // ---- build PV A-fragment in-register: pa[j] = P[cc][kv0+8g+j] (bf16)
    unsigned a0, a1, b0w, b1w;
    asm("v_cvt_pk_bf16_f32 %0, %1, %2" : "=v"(a0) : "v"(p0[0]), "v"(p0[1]));
    asm("v_cvt_pk_bf16_f32 %0, %1, %2" : "=v"(a1) : "v"(p0[2]), "v"(p0[3]));
    asm("v_cvt_pk_bf16_f32 %0, %1, %2" : "=v"(b0w) : "v"(p1[0]), "v"(p1[1]));
    asm("v_cvt_pk_bf16_f32 %0, %1, %2" : "=v"(b1w) : "v"(p1[2]), "v"(p1[3]));
    const int srcLo = cc + ((g & 1) << 5);  // lane of source group 2*(g&1)
    const int srcHi = srcLo + 16;           // lane of source group 2*(g&1)+1
    unsigned wa0 = (unsigned)__shfl((int)a0, srcLo);
    unsigned wa1 = (unsigned)__shfl((int)a1, srcLo);
    unsigned wa2 = (unsigned)__shfl((int)a0, srcHi);
    unsigned wa3 = (unsigned)__shfl((int)a1, srcHi);
    unsigned wb0 = (unsigned)__shfl((int)b0w, srcLo);
    unsigned wb1 = (unsigned)__shfl((int)b1w, srcLo);
    unsigned wb2 = (unsigned)__shfl((int)b0w, srcHi);
    unsigned wb3 = (unsigned)__shfl((int)b1w, srcHi);
    const bool hiHalf = (g >= 2);
    u32x4 paw = {hiHalf ? wb0 : wa0, hiHalf ? wb1 : wa1,
                 hiHalf ? wb2 : wa2, hiHalf ? wb3 : wa3};
    short8 pa = __builtin_bit_cast(short8, paw);

    // ---- O += P V: B-fragment = ONE ds_read_b128 from V^T tile per ft.
    const unsigned va = (unsigned)(uintptr_t)&Vs[tix & 1][0] + cc * 64 + g * 16;
    short8 vb[16];
#pragma unroll
    for (int ft = 0; ft < 16; ++ft) {
      asm volatile("ds_read_b128 %0, %1 offset:%2"
                   : "=&v"(vb[ft]) : "v"(va), "i"(ft * 1024) : "memory");
    }
    asm volatile("s_waitcnt lgkmcnt(8)" ::: "memory");  // ft 0..7 done
    __builtin_amdgcn_sched_barrier(0);
    __builtin_amdgcn_s_setprio(1);
#pragma unroll
    for (int ft = 0; ft < 8; ++ft) {
      acc[ft] = __builtin_amdgcn_mfma_f32_16x16x32_bf16(pa, vb[ft], acc[ft], 0, 0, 0);
    }
    __builtin_amdgcn_s_setprio(0);
    asm volatile("s_waitcnt lgkmcnt(0)" ::: "memory");
    __builtin_amdgcn_sched_barrier(0);
    __builtin_amdgcn_s_setprio(1);
#pragma unroll
    for (int ft = 8; ft < 16; ++ft) {
      acc[ft] = __builtin_amdgcn_mfma_f32_16x16x32_bf16(pa, vb[ft], acc[ft], 0, 0, 0);
    }
    __builtin_amdgcn_s_setprio(0);

    // ---- all waves done reading tile-t buffers before next iteration's
    // issues overwrite them (raw barrier: no counter drain)
    __builtin_amdgcn_sched_barrier(0);
    __builtin_amdgcn_s_barrier();
    __builtin_amdgcn_sched_barrier(0);
  }

  // ---- epilogue: reduce deferred l across the row's 4 lanes
  l_run += __shfl_xor(l_run, 16);
  l_run += __shfl_xor(l_run, 32);

  // transpose acc through LDS (reuse Ks, 48 KB available)
  unsigned short* sc = &Ks[0][0];
#pragma unroll
  for (int ft = 0; ft < 16; ++ft) {
#pragma unroll
    for (int r = 0; r < 4; ++r) {
      sc[(16 * wv + 4 * g + r) * 256 + ft * 16 + cc] = bf16rne(acc[ft][r]);
    }
  }
  if (g == 0) {  // lane owns row cc: one writer per row
    ppM[16 * wv + cc] = m_run;
    ppL[16 * wv + cc] = l_run;
  }
  __syncthreads();
  {
    const int row = tid >> 2, q4 = tid & 3;
    const unsigned short* srow = sc + row * 256 + q4 * 64;
#pragma unroll
    for (int kk = 0; kk < 8; ++kk) {
      *(ushort8*)(ppA + (size_t)row * ND + q4 * 64 + kk * 8) =
          *(const ushort8*)(srow + kk * 8);
    }
  }
}

// Exact log-sum-exp merge of the variable-count partials per (b, q-tile).
// Grid 1024 (16 rows/block): memory-bound kernel needs the TLP (G11).
__global__ __launch_bounds__(256)
void attn_combine(const unsigned char* __restrict__ ws, float* __restrict__ Og) {
  const int bid = blockIdx.x;        // b(3) | qt(5) | quarter(2)
  const int b = bid >> 7;
  const int qt = (bid >> 2) & 31;
  const int qu = bid & 3;
  const int tid = threadIdx.x;
  const int row = qu * 16 + (tid >> 4);  // 0..63
  const int colb = (tid & 15) * 16;      // 16 cols per thread

  int pbase = 0, nc = 7;
  if (qt > 0) {
    pbase = 7;
    for (int j = 1; j < qt; ++j) pbase += (2 * j + 2 + CHUNK - 1) / CHUNK;
    nc = (2 * qt + 2 + CHUNK - 1) / CHUNK;
  }
  const unsigned char* p0 = ws + WS_P + (size_t)(b * NCHUNKS_B + pbase) * PART_BYTES;

  float M = -3.0e38f;
  for (int c = 0; c < nc; ++c) {
    M = fmaxf(M, *(const float*)(p0 + (size_t)c * PART_BYTES + QB * ND * 2 + row * 4));
  }
  float L = 0.f;
  float o[16];
#pragma unroll
  for (int j = 0; j < 16; ++j) o[j] = 0.f;
  for (int c = 0; c < nc; ++c) {
    const unsigned char* pc = p0 + (size_t)c * PART_BYTES;
    float mm = *(const float*)(pc + QB * ND * 2 + row * 4);
    float ll = *(const float*)(pc + QB * ND * 2 + QB * 4 + row * 4);
    float s = __expf(mm - M);
    L += ll * s;
    const unsigned short* pa =
        (const unsigned short*)pc + (size_t)row * ND + colb;
#pragma unroll
    for (int kk = 0; kk < 2; ++kk) {
      ushort8 a = *(const ushort8*)(pa + kk * 8);
#pragma unroll
      for (int j = 0; j < 8; ++j) {
        unsigned u = ((unsigned)a[j]) << 16;
        o[kk * 8 + j] += __builtin_bit_cast(float, u) * s;
      }
    }
  }
  const float invL = 1.0f / L;
  float* op = Og + ((size_t)b * NL + qt * QB + row) * ND + colb;
#pragma unroll
  for (int kk = 0; kk < 4; ++kk) {
    float4 v = {o[kk * 4] * invL, o[kk * 4 + 1] * invL, o[kk * 4 + 2] * invL,
                o[kk * 4 + 3] * invL};
    *(float4*)(op + kk * 4) = v;
  }
}

extern "C" void kernel_launch(void* const* d_in, const int* in_sizes, int n_in,
                              void* d_out, int out_size, void* d_ws, size_t ws_size,
                              hipStream_t stream) {
  (void)in_sizes; (void)n_in; (void)out_size; (void)ws_size;  // ~49.3MB <= 67.6MB proven (r5)
  const float* Q = (const float*)d_in[0];
  const float* K = (const float*)d_in[1];
  const float* V = (const float*)d_in[2];
  const int* M = (const int*)d_in[3];
  unsigned char* ws = (unsigned char*)d_ws;

  convert_kv<<<dim3(513), dim3(128), 0, stream>>>(K, V, (const unsigned*)M, ws);
  attn_fwd<<<dim3(8 * NCHUNKS_B), dim3(256), 0, stream>>>(
      Q, (const unsigned*)(ws + WS_MB), ws);
  attn_combine<<<dim3(1024), dim3(256), 0, stream>>>(ws, (float*)d_out);
}

// Round 21
// 94.990 us; speedup vs baseline: 2.5882x; 1.0600x over previous
//
#include <hip/hip_runtime.h>
#include <stdint.h>

#define NL 2048
#define ND 256
#define KVB 32
#define QB 64
#define NQT 32                      // 64-row q-tiles per batch
#define NT_ALL (NL / KVB)           // 64 kv tiles per batch
#define CHUNK 10                    // kv tiles per block -> 125 chunks/batch, grid 1000
#define NCHUNKS_B 125               // 7 (qt=0 spans all 64) + sum_{qt=1..31} ceil((2qt+2)/10)
#define TILE_BYTES (KVB * ND * 2)   // 16 KB image per kv tile
#define IMG (8 * NT_ALL * TILE_BYTES)
#define WS_MB 256                   // 512 u32 packed mask bits (2 KB)
#define WS_K (WS_MB + 2048)
#define WS_V (WS_K + IMG)           // V in tr-read subtiled layout (16B stores)
#define WS_P (WS_V + IMG)
#define PART_BYTES (QB * ND * 2 + QB * 8)  // bf16 acc + fp32 m,l = 33280

typedef __attribute__((ext_vector_type(8))) short short8;
typedef __attribute__((ext_vector_type(4))) short short4v;
typedef __attribute__((ext_vector_type(4))) float f32x4;
typedef __attribute__((ext_vector_type(4))) unsigned int u32x4;
typedef __attribute__((ext_vector_type(8))) unsigned short ushort8;

__device__ __forceinline__ unsigned short bf16rne(float x) {
  unsigned u = __builtin_bit_cast(unsigned, x);
  u += 0x7FFFu + ((u >> 16) & 1u);
  return (unsigned short)(u >> 16);
}

__device__ __forceinline__ short8 cvt8(float4 a, float4 b, float scale) {
  short8 v;
  v[0] = (short)bf16rne(a.x * scale);
  v[1] = (short)bf16rne(a.y * scale);
  v[2] = (short)bf16rne(a.z * scale);
  v[3] = (short)bf16rne(a.w * scale);
  v[4] = (short)bf16rne(b.x * scale);
  v[5] = (short)bf16rne(b.y * scale);
  v[6] = (short)bf16rne(b.z * scale);
  v[7] = (short)bf16rne(b.w * scale);
  return v;
}

// One-shot K,V fp32->bf16 conversion. K stored as XOR-swizzled LDS tile
// images; V in the tr-read subtiled layout (ALL stores 16B -> coalesced;
// the r19 V^T layout's 2B scattered stores cost ~6us of convert time).
// Block 512 packs the padding mask (fused mask_pack: one fewer dispatch).
__global__ __launch_bounds__(128)
void convert_kv(const float* __restrict__ K, const float* __restrict__ V,
                const unsigned* __restrict__ M, unsigned char* __restrict__ ws) {
  if (blockIdx.x == 512) {
    __shared__ int badS;
    if (threadIdx.x == 0) badS = 0;
    __syncthreads();
    bool bad = false;
    for (int i = threadIdx.x; i < 4096; i += 128)
      if (M[i] > 1u) bad = true;
    if (__any(bad) && (threadIdx.x & 63) == 0) badS = 1;
    __syncthreads();
    const int byteMode = badS;
    unsigned* MB = (unsigned*)(ws + WS_MB);
    for (int t = threadIdx.x; t < 512; t += 128) {
      unsigned m = 0;
      for (int j = 0; j < 32; ++j) {
        int mv = byteMode ? (int)((const unsigned char*)M)[t * 32 + j]
                          : (int)M[t * 32 + j];
        m |= (mv ? 1u : 0u) << j;
      }
      MB[t] = m;
    }
    return;
  }
  const int t = blockIdx.x;  // b*64 + tix  (32-row tiles)
  const int b = t >> 6, tix = t & 63;
  const float* kt = K + ((size_t)b * NL + tix * KVB) * ND;
  const float* vt = V + ((size_t)b * NL + tix * KVB) * ND;
  unsigned char* kd = ws + WS_K + (size_t)t * TILE_BYTES;
  unsigned char* vd = ws + WS_V + (size_t)t * TILE_BYTES;
#pragma unroll
  for (int it = 0; it < 8; ++it) {
    int idx = it * 128 + threadIdx.x;
    int row = idx >> 5, u = idx & 31, f = u * 8;
    const float4* kp = (const float4*)(kt + (size_t)row * ND + f);
    int kb = (row * 512 + f * 2) ^ ((row & 7) << 4);
    *(short8*)(kd + kb) = cvt8(kp[0], kp[1], 1.0f);
    const float4* vp = (const float4*)(vt + (size_t)row * ND + f);
    int vb = (row >> 2) * 2048 + (u >> 1) * 128 + (row & 3) * 32 + (u & 1) * 16;
    *(short8*)(vd + vb) = cvt8(vp[0], vp[1], 1.0f);
  }
}

// Flash attention fwd [FROZEN r16 structure — LDS-throughput/latency
// equilibrium]: swapped-QK in-register softmax, counted-vmcnt pipeline
// (K 3-buf, V 2-buf, 80 KB LDS, raw barriers), PV via ds_read_b64_tr_b16.
// Defer-max; deferred l-reduce. qt=0 spans all 64 kv tiles (-10000-tier
// tie semantics via the LSE combine).
__global__ __launch_bounds__(256, 2)
void attn_fwd(const float* __restrict__ Qg, const unsigned* __restrict__ MBg,
              unsigned char* ws) {
  __shared__ unsigned short Ks[3][KVB * ND];   // 48 KB (also epilogue scratch)
  __shared__ unsigned short Vs[2][KVB * ND];   // 32 KB (tr-read subtiled)

  const int tid = threadIdx.x;
  const int wv = tid >> 6;      // wave 0..3
  const int lane = tid & 63;
  const int g = lane >> 4;      // 4-lane-group id
  const int cc = lane & 15;     // lane-in-group

  // ---- decode fid -> (b, qt, c)
  const int fid = blockIdx.x;
  const int b = fid / NCHUNKS_B;
  int rem = fid - b * NCHUNKS_B;
  int qt = 0, c = 0, pbase = 0;
  if (rem < 7) {
    qt = 0; c = rem; pbase = 0;
  } else {
    rem -= 7; pbase = 7;
    for (qt = 1; qt < NQT; ++qt) {
      int ncq = (2 * qt + 2 + CHUNK - 1) / CHUNK;
      if (rem < ncq) { c = rem; break; }
      rem -= ncq; pbase += ncq;
    }
  }
  const int qb = qt * QB;
  const int nt_s = (qt == 0) ? NT_ALL : (2 * qt + 2);
  const int t0 = c * CHUNK;
  const int t1 = min(nt_s, t0 + CHUNK);
  unsigned char* pp = ws + WS_P + (size_t)(b * NCHUNKS_B + pbase + c) * PART_BYTES;
  unsigned short* ppA = (unsigned short*)pp;
  float* ppM = (float*)(pp + QB * ND * 2);
  float* ppL = ppM + QB;

  auto stage_K = [&](int tix, int bi) {
    const unsigned char* kg = ws + WS_K + ((size_t)(b * NT_ALL + tix)) * TILE_BYTES;
#pragma unroll
    for (int s = 0; s < 4; ++s) {
      const int seg = wv * 4 + s;  // wave-uniform LDS dest; per-lane global src
      __builtin_amdgcn_global_load_lds(
          (const __attribute__((address_space(1))) unsigned int*)(kg + seg * 1024 + lane * 16),
          (__attribute__((address_space(3))) unsigned int*)((unsigned char*)&Ks[bi][0] + seg * 1024),
          16, 0, 0);
    }
  };
  auto stage_V = [&](int tix, int bi) {
    const unsigned char* vg = ws + WS_V + ((size_t)(b * NT_ALL + tix)) * TILE_BYTES;
#pragma unroll
    for (int s = 0; s < 4; ++s) {
      const int seg = wv * 4 + s;
      __builtin_amdgcn_global_load_lds(
          (const __attribute__((address_space(1))) unsigned int*)(vg + seg * 1024 + lane * 16),
          (__attribute__((address_space(3))) unsigned int*)((unsigned char*)&Vs[bi][0] + seg * 1024),
          16, 0, 0);
    }
  };

  // ---- Q fragments direct from fp32 (once per block), scaled 1/16
  const float* qp = Qg + ((size_t)b * NL + (qb + 16 * wv + cc)) * ND;
  short8 qf[8];
#pragma unroll
  for (int ch = 0; ch < 8; ++ch) {
    int f = ch * 32 + g * 8;
    float4 a0 = *reinterpret_cast<const float4*>(qp + f);
    float4 a1 = *reinterpret_cast<const float4*>(qp + f + 4);
    qf[ch] = cvt8(a0, a1, 0.0625f);
  }
  const int qg = qb + 16 * wv + cc;  // this lane's q-row (swapped layout)

  f32x4 acc[16];
#pragma unroll
  for (int i = 0; i < 16; ++i) acc[i] = (f32x4){0.f, 0.f, 0.f, 0.f};
  float m_run = -3.0e38f, l_run = 0.f;   // per-lane scalars (row = cc)

  // ---- prologue: retire Q loads (FIFO must contain only DMA), then prime
  // the pipe: K(t0), K(t0+1) [both OLDER than V(t0) so steady counts hold].
  asm volatile("s_waitcnt vmcnt(0)" ::: "memory");
  __builtin_amdgcn_sched_barrier(0);
  stage_K(t0, t0 % 3);
  if (t0 + 1 < t1) stage_K(t0 + 1, (t0 + 1) % 3);
  stage_V(t0, t0 & 1);

  for (int tix = t0; tix < t1; ++tix) {
    // issue next K/V into buffers freed by the barrier ending the previous
    // iteration (K 2-deep, V 1-deep prefetch)
    if (tix + 2 < t1) stage_K(tix + 2, (tix + 2) % 3);
    if (tix + 1 < t1) stage_V(tix + 1, (tix + 1) & 1);
    // counted wait: retire own K(t),V(t); newer prefetch stays in flight
    if (tix + 2 < t1) {
      asm volatile("s_waitcnt vmcnt(8)" ::: "memory");
    } else if (tix + 1 < t1) {
      asm volatile("s_waitcnt vmcnt(4)" ::: "memory");
    } else {
      asm volatile("s_waitcnt vmcnt(0)" ::: "memory");
    }
    __builtin_amdgcn_sched_barrier(0);
    __builtin_amdgcn_s_barrier();   // all waves' tile-t staging visible
    __builtin_amdgcn_sched_barrier(0);

    const int kv0 = tix * KVB;
    const unsigned mb = MBg[b * NT_ALL + tix];  // wave-uniform -> s_load

    // ---- S^T = K Q^T: lane (g,cc) gets S[q=cc][kv0+4g+r] (s0), +16 (s1)
    const char* ksB = (const char*)&Ks[tix % 3][0];
    f32x4 s0 = {0.f, 0.f, 0.f, 0.f}, s1 = {0.f, 0.f, 0.f, 0.f};
    __builtin_amdgcn_s_setprio(1);
#pragma unroll
    for (int ch = 0; ch < 8; ++ch) {
      int cbase = ch * 64 + g * 16;
      int b0 = (cc * 512 + cbase) ^ ((cc & 7) << 4);
      int b1 = ((cc + 16) * 512 + cbase) ^ ((cc & 7) << 4);
      short8 k0 = *reinterpret_cast<const short8*>(ksB + b0);
      short8 k1 = *reinterpret_cast<const short8*>(ksB + b1);
      s0 = __builtin_amdgcn_mfma_f32_16x16x32_bf16(k0, qf[ch], s0, 0, 0, 0);
      s1 = __builtin_amdgcn_mfma_f32_16x16x32_bf16(k1, qf[ch], s1, 0, 0, 0);
    }
    __builtin_amdgcn_s_setprio(0);

    // ---- biases: padding from packed bits + causal, per element
#pragma unroll
    for (int r = 0; r < 4; ++r) {
      int k0i = 4 * g + r, k1i = 16 + 4 * g + r;
      if (!((mb >> k0i) & 1u)) s0[r] -= 10000.f;
      if (!((mb >> k1i) & 1u)) s1[r] -= 10000.f;
      if (kv0 + k0i > qg) s0[r] -= 10000.f;
      if (kv0 + k1i > qg) s1[r] -= 10000.f;
    }

    // ---- online softmax, row-local: in-lane tree + 2 cross-lane rounds
    float rmax = fmaxf(fmaxf(fmaxf(s0[0], s0[1]), fmaxf(s0[2], s0[3])),
                       fmaxf(fmaxf(s1[0], s1[1]), fmaxf(s1[2], s1[3])));
    rmax = fmaxf(rmax, __shfl_xor(rmax, 16));
    rmax = fmaxf(rmax, __shfl_xor(rmax, 32));
    bool grow = (rmax > m_run + 8.f);
    if (__any(grow)) {  // wave-uniform; exact in the LSE combine
      float mn = fmaxf(m_run, rmax);
      float alpha = __expf(m_run - mn);
      m_run = mn;
      l_run *= alpha;   // per-lane partial l; alpha row-uniform -> exact
      f32x4 av;
#pragma unroll
      for (int r = 0; r < 4; ++r) av[r] = __shfl(alpha, 20 * g + r);
#pragma unroll
      for (int i = 0; i < 16; ++i) acc[i] *= av;
    }
    float p0[4], p1[4];
#pragma unroll
    for (int r = 0; r < 4; ++r) {
      p0[r] = __expf(s0[r] - m_run);
      p1[r] = __expf(s1[r] - m_run);
    }
    // deferred l: accumulate per-lane partial only (reduced in epilogue)
    l_run += (p0[0] + p0[1]) + (p0[2] + p0[3]) +
             (p1[0] + p1[1]) + (p1[2] + p1[3]);

    // ---- build PV A-fragment in-register: pa[j] = P[cc][kv0+8g+j] (bf16)
    unsigned a0, a1, b0w, b1w;
    asm("v_cvt_pk_bf16_f32 %0, %1, %2" : "=v"(a0) : "v"(p0[0]), "v"(p0[1]));
    asm("v_cvt_pk_bf16_f32 %0, %1, %2" : "=v"(a1) : "v"(p0[2]), "v"(p0[3]));
    asm("v_cvt_pk_bf16_f32 %0, %1, %2" : "=v"(b0w) : "v"(p1[0]), "v"(p1[1]));
    asm("v_cvt_pk_bf16_f32 %0, %1, %2" : "=v"(b1w) : "v"(p1[2]), "v"(p1[3]));
    const int srcLo = cc + ((g & 1) << 5);  // lane of source group 2*(g&1)
    const int srcHi = srcLo + 16;           // lane of source group 2*(g&1)+1
    unsigned wa0 = (unsigned)__shfl((int)a0, srcLo);
    unsigned wa1 = (unsigned)__shfl((int)a1, srcLo);
    unsigned wa2 = (unsigned)__shfl((int)a0, srcHi);
    unsigned wa3 = (unsigned)__shfl((int)a1, srcHi);
    unsigned wb0 = (unsigned)__shfl((int)b0w, srcLo);
    unsigned wb1 = (unsigned)__shfl((int)b1w, srcLo);
    unsigned wb2 = (unsigned)__shfl((int)b0w, srcHi);
    unsigned wb3 = (unsigned)__shfl((int)b1w, srcHi);
    const bool hiHalf = (g >= 2);
    u32x4 paw = {hiHalf ? wb0 : wa0, hiHalf ? wb1 : wa1,
                 hiHalf ? wb2 : wa2, hiHalf ? wb3 : wa3};
    short8 pa = __builtin_bit_cast(short8, paw);

    // ---- O += P V: 32 tr-reads issued; counted lgkmcnt(15) overlaps the
    // first MFMA batch with in-flight tr-reads (DS completes in order).
    const unsigned va = (unsigned)(uintptr_t)&Vs[tix & 1][0] + g * 4096 + cc * 8;
    short4v lo[16], hi[16];
#pragma unroll
    for (int ft = 0; ft < 16; ++ft) {
      asm volatile("ds_read_b64_tr_b16 %0, %1 offset:%2"
                   : "=&v"(lo[ft]) : "v"(va), "i"(ft * 128) : "memory");
      asm volatile("ds_read_b64_tr_b16 %0, %1 offset:%2"
                   : "=&v"(hi[ft]) : "v"(va), "i"(ft * 128 + 2048) : "memory");
    }
    asm volatile("s_waitcnt lgkmcnt(15)" ::: "memory");  // >=17 done: ft 0..7
    __builtin_amdgcn_sched_barrier(0);
    __builtin_amdgcn_s_setprio(1);
#pragma unroll
    for (int ft = 0; ft < 8; ++ft) {
      short8 vb = __builtin_shufflevector(lo[ft], hi[ft], 0, 1, 2, 3, 4, 5, 6, 7);
      acc[ft] = __builtin_amdgcn_mfma_f32_16x16x32_bf16(pa, vb, acc[ft], 0, 0, 0);
    }
    __builtin_amdgcn_s_setprio(0);
    asm volatile("s_waitcnt lgkmcnt(0)" ::: "memory");
    __builtin_amdgcn_sched_barrier(0);
    __builtin_amdgcn_s_setprio(1);
#pragma unroll
    for (int ft = 8; ft < 16; ++ft) {
      short8 vb = __builtin_shufflevector(lo[ft], hi[ft], 0, 1, 2, 3, 4, 5, 6, 7);
      acc[ft] = __builtin_amdgcn_mfma_f32_16x16x32_bf16(pa, vb, acc[ft], 0, 0, 0);
    }
    __builtin_amdgcn_s_setprio(0);

    // ---- all waves done reading tile-t buffers before next iteration's
    // issues overwrite them (raw barrier: no counter drain)
    __builtin_amdgcn_sched_barrier(0);
    __builtin_amdgcn_s_barrier();
    __builtin_amdgcn_sched_barrier(0);
  }

  // ---- epilogue: reduce deferred l across the row's 4 lanes
  l_run += __shfl_xor(l_run, 16);
  l_run += __shfl_xor(l_run, 32);

  // transpose acc through LDS (reuse Ks, 48 KB available)
  unsigned short* sc = &Ks[0][0];
#pragma unroll
  for (int ft = 0; ft < 16; ++ft) {
#pragma unroll
    for (int r = 0; r < 4; ++r) {
      sc[(16 * wv + 4 * g + r) * 256 + ft * 16 + cc] = bf16rne(acc[ft][r]);
    }
  }
  if (g == 0) {  // lane owns row cc: one writer per row
    ppM[16 * wv + cc] = m_run;
    ppL[16 * wv + cc] = l_run;
  }
  __syncthreads();
  {
    const int row = tid >> 2, q4 = tid & 3;
    const unsigned short* srow = sc + row * 256 + q4 * 64;
#pragma unroll
    for (int kk = 0; kk < 8; ++kk) {
      *(ushort8*)(ppA + (size_t)row * ND + q4 * 64 + kk * 8) =
          *(const ushort8*)(srow + kk * 8);
    }
  }
}

// Exact log-sum-exp merge of the variable-count partials per (b, q-tile).
// Grid 1024 (16 rows/block): memory-bound kernel needs the TLP (G11).
__global__ __launch_bounds__(256)
void attn_combine(const unsigned char* __restrict__ ws, float* __restrict__ Og) {
  const int bid = blockIdx.x;        // b(3) | qt(5) | quarter(2)
  const int b = bid >> 7;
  const int qt = (bid >> 2) & 31;
  const int qu = bid & 3;
  const int tid = threadIdx.x;
  const int row = qu * 16 + (tid >> 4);  // 0..63
  const int colb = (tid & 15) * 16;      // 16 cols per thread

  int pbase = 0, nc = 7;
  if (qt > 0) {
    pbase = 7;
    for (int j = 1; j < qt; ++j) pbase += (2 * j + 2 + CHUNK - 1) / CHUNK;
    nc = (2 * qt + 2 + CHUNK - 1) / CHUNK;
  }
  const unsigned char* p0 = ws + WS_P + (size_t)(b * NCHUNKS_B + pbase) * PART_BYTES;

  float M = -3.0e38f;
  for (int c = 0; c < nc; ++c) {
    M = fmaxf(M, *(const float*)(p0 + (size_t)c * PART_BYTES + QB * ND * 2 + row * 4));
  }
  float L = 0.f;
  float o[16];
#pragma unroll
  for (int j = 0; j < 16; ++j) o[j] = 0.f;
  for (int c = 0; c < nc; ++c) {
    const unsigned char* pc = p0 + (size_t)c * PART_BYTES;
    float mm = *(const float*)(pc + QB * ND * 2 + row * 4);
    float ll = *(const float*)(pc + QB * ND * 2 + QB * 4 + row * 4);
    float s = __expf(mm - M);
    L += ll * s;
    const unsigned short* pa =
        (const unsigned short*)pc + (size_t)row * ND + colb;
#pragma unroll
    for (int kk = 0; kk < 2; ++kk) {
      ushort8 a = *(const ushort8*)(pa + kk * 8);
#pragma unroll
      for (int j = 0; j < 8; ++j) {
        unsigned u = ((unsigned)a[j]) << 16;
        o[kk * 8 + j] += __builtin_bit_cast(float, u) * s;
      }
    }
  }
  const float invL = 1.0f / L;
  float* op = Og + ((size_t)b * NL + qt * QB + row) * ND + colb;
#pragma unroll
  for (int kk = 0; kk < 4; ++kk) {
    float4 v = {o[kk * 4] * invL, o[kk * 4 + 1] * invL, o[kk * 4 + 2] * invL,
                o[kk * 4 + 3] * invL};
    *(float4*)(op + kk * 4) = v;
  }
}

extern "C" void kernel_launch(void* const* d_in, const int* in_sizes, int n_in,
                              void* d_out, int out_size, void* d_ws, size_t ws_size,
                              hipStream_t stream) {
  (void)in_sizes; (void)n_in; (void)out_size; (void)ws_size;  // ~49.3MB <= 67.6MB proven (r5)
  const float* Q = (const float*)d_in[0];
  const float* K = (const float*)d_in[1];
  const float* V = (const float*)d_in[2];
  const int* M = (const int*)d_in[3];
  unsigned char* ws = (unsigned char*)d_ws;

  convert_kv<<<dim3(513), dim3(128), 0, stream>>>(K, V, (const unsigned*)M, ws);
  attn_fwd<<<dim3(8 * NCHUNKS_B), dim3(256), 0, stream>>>(
      Q, (const unsigned*)(ws + WS_MB), ws);
  attn_combine<<<dim3(1024), dim3(256), 0, stream>>>(ws, (float*)d_out);
}